// Round 12
// baseline (447.074 us; speedup 1.0000x reference)
//
#include <hip/hip_runtime.h>
#include <hip/hip_bf16.h>

#define N_NODES 50000
#define N_EDGES 800000
#define N_GRAPHS 64
#define FEAT 128
#define EMB 256
#define HID 512
#define VOCAB 512

#define SCAN_B 256
#define SCAN_NB ((N_NODES + SCAN_B - 1) / SCAN_B)   // 196
#define RB ((N_NODES + 127) / 128)                  // 391 row-blocks
#define RPX ((RB + 7) / 8)                          // 49 row-blocks per XCD

typedef __attribute__((ext_vector_type(8))) short short8;
typedef __attribute__((ext_vector_type(4))) float floatx4;
typedef __attribute__((ext_vector_type(2))) float floatx2;
typedef unsigned short ushort_t;
typedef unsigned int uint32;
typedef unsigned char uchar_t;

__device__ __forceinline__ ushort_t f2b(float f) {
    uint32 u = __builtin_bit_cast(uint32, f);
    u += 0x7fffu + ((u >> 16) & 1u);
    return (ushort_t)(u >> 16);
}
__device__ __forceinline__ float b2f(ushort_t h) {
    uint32 u = ((uint32)h) << 16;
    return __builtin_bit_cast(float, u);
}
// u holds bf16 pair [even, odd]; accumulate into a (even) and b (odd)
__device__ __forceinline__ void acc2(uint32 u, float& a, float& b) {
    a += __builtin_bit_cast(float, u << 16);
    b += __builtin_bit_cast(float, u & 0xffff0000u);
}
// u holds 4 fp8 e4m3; accumulate into a[0..3]
__device__ __forceinline__ void accf8(uint32 u, float* a) {
    floatx2 lo = __builtin_amdgcn_cvt_pk_f32_fp8(u, false);
    floatx2 hi = __builtin_amdgcn_cvt_pk_f32_fp8(u, true);
    a[0] += lo[0]; a[1] += lo[1]; a[2] += hi[0]; a[3] += hi[1];
}
__device__ __forceinline__ uchar_t f2f8(float v) {
    return (uchar_t)(__builtin_amdgcn_cvt_pk_fp8_f32(v, v, 0, false) & 0xff);
}
__device__ __forceinline__ void async16(const void* g, void* l) {
    __builtin_amdgcn_global_load_lds(
        (const __attribute__((address_space(1))) void*)g,
        (__attribute__((address_space(3))) void*)l, 16, 0, 0);
}

// ---------------- CSR build ----------------

__global__ void deg_kernel(const int* __restrict__ edge, int* __restrict__ deg) {
    int e = blockIdx.x * blockDim.x + threadIdx.x;
    if (e < N_EDGES) atomicAdd(deg + edge[N_EDGES + e], 1);
}

// ---- 3-phase parallel exclusive scan of deg -> offsets (+ fused rinv/cursor/ncnt) ----
__global__ __launch_bounds__(SCAN_B) void scan_part_kernel(const int* __restrict__ deg,
                                                           int* __restrict__ blocksum) {
    __shared__ int s[SCAN_B];
    int i = blockIdx.x * SCAN_B + threadIdx.x;
    int t = threadIdx.x;
    s[t] = (i < N_NODES) ? deg[i] : 0;
    __syncthreads();
    #pragma unroll
    for (int off = SCAN_B / 2; off > 0; off >>= 1) {
        if (t < off) s[t] += s[t + off];
        __syncthreads();
    }
    if (t == 0) blocksum[blockIdx.x] = s[0];
}

// scan of block sums + (threads 0..63) ncnt via binary search on sorted batch
__global__ __launch_bounds__(SCAN_B) void scan_base_kernel(const int* __restrict__ blocksum,
                                                           int* __restrict__ blockbase,
                                                           const int* __restrict__ batch,
                                                           float* __restrict__ ncnt) {
    __shared__ int s[SCAN_B];
    int t = threadIdx.x;
    int v = (t < SCAN_NB) ? blocksum[t] : 0;
    s[t] = v;
    __syncthreads();
    #pragma unroll
    for (int off = 1; off < SCAN_B; off <<= 1) {
        int u = (t >= off) ? s[t - off] : 0;
        __syncthreads();
        s[t] += u;
        __syncthreads();
    }
    blockbase[t] = s[t] - v;   // exclusive
    if (t < N_GRAPHS) {
        int g = t;
        int lo = 0, hi = N_NODES;
        while (lo < hi) { int mid = (lo + hi) >> 1; if (batch[mid] < g) lo = mid + 1; else hi = mid; }
        int lo2 = lo, hi2 = N_NODES;
        while (lo2 < hi2) { int mid = (lo2 + hi2) >> 1; if (batch[mid] < g + 1) lo2 = mid + 1; else hi2 = mid; }
        ncnt[g] = (float)(lo2 - lo);
    }
}

__global__ __launch_bounds__(SCAN_B) void scan_final_kernel(const int* __restrict__ deg,
                                                            const int* __restrict__ blockbase,
                                                            int* __restrict__ offsets,
                                                            int* __restrict__ cursor,
                                                            float* __restrict__ rinv) {
    __shared__ int s[SCAN_B];
    int i = blockIdx.x * SCAN_B + threadIdx.x;
    int t = threadIdx.x;
    int v = (i < N_NODES) ? deg[i] : 0;
    s[t] = v;
    __syncthreads();
    #pragma unroll
    for (int off = 1; off < SCAN_B; off <<= 1) {
        int u = (t >= off) ? s[t - off] : 0;
        __syncthreads();
        s[t] += u;
        __syncthreads();
    }
    int excl = s[t] - v + blockbase[blockIdx.x];
    if (i < N_NODES) {
        offsets[i] = excl;
        cursor[i] = excl;          // fill uses cursor directly (abs position)
        rinv[i] = 1.0f / (float)max(v, 1);
    }
    if (i == N_NODES - 1) offsets[N_NODES] = excl + v;
}

__global__ void fill_kernel(const int* __restrict__ edge,
                            int* __restrict__ cursor, int* __restrict__ srcbuf) {
    int e = blockIdx.x * blockDim.x + threadIdx.x;
    if (e < N_EDGES) {
        int src = edge[e];
        int dst = edge[N_EDGES + e];
        int pos = atomicAdd(cursor + dst, 1);   // cursor pre-initialized to offsets
        srcbuf[pos] = src;
    }
}

// ---------------- converts ----------------

__global__ void conv_x_kernel(const float* __restrict__ x, ushort_t* __restrict__ xb) {
    int tid = blockIdx.x * blockDim.x + threadIdx.x;   // N_NODES*32
    int row = tid >> 5, c = (tid & 31) * 4;
    float4 v = *(const float4*)(x + (size_t)row * FEAT + c);
    ushort4 o;
    o.x = f2b(v.x); o.y = f2b(v.y); o.z = f2b(v.z); o.w = f2b(v.w);
    *(ushort4*)(xb + (size_t)row * (2 * FEAT) + c) = o;
}

// both weight transposes in one launch:
// tid < 256*256 -> w1t[n][k] from W01/W11 (K1=128, N=256)
// else          -> w2t[n][k] from W02/W12 (K1=256, N=512)
__global__ void conv_wt2_kernel(const float* __restrict__ W01, const float* __restrict__ W11,
                                const float* __restrict__ W02, const float* __restrict__ W12,
                                ushort_t* __restrict__ w1t, ushort_t* __restrict__ w2t) {
    int tid = blockIdx.x * blockDim.x + threadIdx.x;
    if (tid < 256 * 256) {
        int n = tid >> 8, k = tid & 255;
        float v = (k < 128) ? W01[(size_t)k * 256 + n] : W11[(size_t)(k - 128) * 256 + n];
        w1t[tid] = f2b(v);
    } else {
        int t2 = tid - 256 * 256;
        int n = t2 >> 9, k = t2 & 511;
        float v = (k < 256) ? W02[(size_t)k * 512 + n] : W12[(size_t)(k - 256) * 512 + n];
        w2t[t2] = f2b(v);
    }
}

// ---------------- CSR gathers ----------------
// gather1: bf16 source; 4 lane-groups of 16 handle 4 edges per instruction
__global__ __launch_bounds__(256) void gather1_kernel(
    const int* __restrict__ offsets, const int* __restrict__ srcbuf,
    const float* __restrict__ rinv, ushort_t* __restrict__ xb)
{
    int node = blockIdx.x * 4 + (threadIdx.x >> 6);
    if (node >= N_NODES) return;
    int lane = threadIdx.x & 63;
    int grp = lane >> 4;          // 0..3 (edge slot)
    int l16 = lane & 15;          // column group: cols l16*8 .. +7
    int beg = offsets[node], end = offsets[node + 1];

    float a[8] = {0.f, 0.f, 0.f, 0.f, 0.f, 0.f, 0.f, 0.f};
    int j = beg + grp;
    for (; j + 4 < end; j += 8) {
        int s0 = srcbuf[j];
        int s1 = srcbuf[j + 4];
        uint4 u0 = *(const uint4*)(xb + (size_t)s0 * 256 + l16 * 8);
        uint4 u1 = *(const uint4*)(xb + (size_t)s1 * 256 + l16 * 8);
        acc2(u0.x, a[0], a[1]); acc2(u0.y, a[2], a[3]);
        acc2(u0.z, a[4], a[5]); acc2(u0.w, a[6], a[7]);
        acc2(u1.x, a[0], a[1]); acc2(u1.y, a[2], a[3]);
        acc2(u1.z, a[4], a[5]); acc2(u1.w, a[6], a[7]);
    }
    for (; j < end; j += 4) {
        int s0 = srcbuf[j];
        uint4 u0 = *(const uint4*)(xb + (size_t)s0 * 256 + l16 * 8);
        acc2(u0.x, a[0], a[1]); acc2(u0.y, a[2], a[3]);
        acc2(u0.z, a[4], a[5]); acc2(u0.w, a[6], a[7]);
    }
    #pragma unroll
    for (int k = 0; k < 8; ++k) a[k] += __shfl_down(a[k], 32);
    #pragma unroll
    for (int k = 0; k < 8; ++k) a[k] += __shfl_down(a[k], 16);
    if (grp == 0) {
        float ri = rinv[node];
        uint4 o;
        o.x = (uint32)f2b(a[0] * ri) | ((uint32)f2b(a[1] * ri) << 16);
        o.y = (uint32)f2b(a[2] * ri) | ((uint32)f2b(a[3] * ri) << 16);
        o.z = (uint32)f2b(a[4] * ri) | ((uint32)f2b(a[5] * ri) << 16);
        o.w = (uint32)f2b(a[6] * ri) | ((uint32)f2b(a[7] * ri) << 16);
        *(uint4*)(xb + (size_t)node * 256 + 128 + l16 * 8) = o;
    }
}

// gather2: fp8 source (256 B/row); 4 lane-groups of 16, lane covers 16 cols
__global__ __launch_bounds__(256) void gather2_kernel(
    const int* __restrict__ offsets, const int* __restrict__ srcbuf,
    const float* __restrict__ rinv, const uchar_t* __restrict__ h1f8,
    ushort_t* __restrict__ h1b)
{
    int node = blockIdx.x * 4 + (threadIdx.x >> 6);
    if (node >= N_NODES) return;
    int lane = threadIdx.x & 63;
    int grp = lane >> 4;          // 0..3 (edge slot)
    int l16 = lane & 15;          // cols l16*16 .. +15
    int beg = offsets[node], end = offsets[node + 1];

    float a[16];
    #pragma unroll
    for (int k = 0; k < 16; ++k) a[k] = 0.f;

    int j = beg + grp;
    for (; j + 4 < end; j += 8) {
        int s0 = srcbuf[j];
        int s1 = srcbuf[j + 4];
        uint4 u0 = *(const uint4*)(h1f8 + (size_t)s0 * 256 + l16 * 16);
        uint4 u1 = *(const uint4*)(h1f8 + (size_t)s1 * 256 + l16 * 16);
        accf8(u0.x, a + 0); accf8(u0.y, a + 4); accf8(u0.z, a + 8); accf8(u0.w, a + 12);
        accf8(u1.x, a + 0); accf8(u1.y, a + 4); accf8(u1.z, a + 8); accf8(u1.w, a + 12);
    }
    for (; j < end; j += 4) {
        int s0 = srcbuf[j];
        uint4 u0 = *(const uint4*)(h1f8 + (size_t)s0 * 256 + l16 * 16);
        accf8(u0.x, a + 0); accf8(u0.y, a + 4); accf8(u0.z, a + 8); accf8(u0.w, a + 12);
    }
    #pragma unroll
    for (int k = 0; k < 16; ++k) a[k] += __shfl_down(a[k], 32);
    #pragma unroll
    for (int k = 0; k < 16; ++k) a[k] += __shfl_down(a[k], 16);
    if (grp == 0) {
        float ri = rinv[node];
        uint4 o0, o1;
        o0.x = (uint32)f2b(a[0] * ri)  | ((uint32)f2b(a[1] * ri) << 16);
        o0.y = (uint32)f2b(a[2] * ri)  | ((uint32)f2b(a[3] * ri) << 16);
        o0.z = (uint32)f2b(a[4] * ri)  | ((uint32)f2b(a[5] * ri) << 16);
        o0.w = (uint32)f2b(a[6] * ri)  | ((uint32)f2b(a[7] * ri) << 16);
        o1.x = (uint32)f2b(a[8] * ri)  | ((uint32)f2b(a[9] * ri) << 16);
        o1.y = (uint32)f2b(a[10] * ri) | ((uint32)f2b(a[11] * ri) << 16);
        o1.z = (uint32)f2b(a[12] * ri) | ((uint32)f2b(a[13] * ri) << 16);
        o1.w = (uint32)f2b(a[14] * ri) | ((uint32)f2b(a[15] * ri) << 16);
        *(uint4*)(h1b + (size_t)node * 512 + 256 + l16 * 16) = o0;
        *(uint4*)(h1b + (size_t)node * 512 + 256 + l16 * 16 + 8) = o1;
    }
}

// ---------------- bf16 MFMA GEMM (128x128 tile, BK=64, XCD-swizzled dispatch) ----------------
// round-10 config: one col-tile per block (col-folding regressed in R11 — A not
// retained in L2 across passes; FETCH 27->38 MB). Grid 8*RPX*COLS, col fastest.
template<int KTOT, int OUTSTR, bool POOL, bool FP8OUT, int COLS>
__global__ __launch_bounds__(256) void mfma_gemm(
    const ushort_t* __restrict__ A, const ushort_t* __restrict__ Bt,
    const float* __restrict__ bias,
    ushort_t* __restrict__ outb, uchar_t* __restrict__ outf8,
    float* __restrict__ psum, const int* __restrict__ batch)
{
    __shared__ ushort_t As[8192];       // 128 x 64 k, 16 KB
    __shared__ ushort_t Bs[8192];       // 128 x 64 k, 16 KB
    __shared__ float pool2[8 * 128];    // POOL reduction scratch (4 KB)

    const int id = blockIdx.x;
    const int xcd = id & 7;
    const int s_ = id >> 3;
    const int col = s_ & (COLS - 1);
    const int rloc = s_ / COLS;
    const int rowblk = xcd * RPX + rloc;
    if (rowblk >= RB) return;

    const int tid = threadIdx.x;
    const int lane = tid & 63;
    const int wave = tid >> 6;
    const int quad = lane >> 4;
    const int l16 = lane & 15;
    const int m0w = (wave & 1) * 64;
    const int n0w = (wave >> 1) * 64;
    const int row0 = rowblk * 128;
    const int col0 = col * 128;
    const int Mm1 = N_NODES - 1;

    int st_r[4], st_q[4];
    #pragma unroll
    for (int c = 0; c < 4; ++c) {
        int slot = c * 256 + tid;
        int r = slot >> 3;
        st_r[c] = r;
        st_q[c] = ((slot & 7) ^ (r & 7)) * 8;
    }

    floatx4 acc[4][4] = {};

    for (int kt = 0; kt < KTOT / 64; ++kt) {
        const int kb = kt * 64;
        #pragma unroll
        for (int c = 0; c < 4; ++c) {
            async16(A + (size_t)min(row0 + st_r[c], Mm1) * KTOT + kb + st_q[c],
                    &As[(c * 256 + wave * 64) * 8]);
        }
        #pragma unroll
        for (int c = 0; c < 4; ++c) {
            async16(Bt + (size_t)(col0 + st_r[c]) * KTOT + kb + st_q[c],
                    &Bs[(c * 256 + wave * 64) * 8]);
        }
        __syncthreads();
        #pragma unroll
        for (int kk = 0; kk < 2; ++kk) {
            short8 a[4], b[4];
            #pragma unroll
            for (int t = 0; t < 4; ++t) {
                int r = m0w + t * 16 + l16;
                a[t] = *(const short8*)&As[r * 64 + (((kk * 4 + quad) ^ (r & 7)) * 8)];
            }
            #pragma unroll
            for (int t = 0; t < 4; ++t) {
                int r = n0w + t * 16 + l16;
                b[t] = *(const short8*)&Bs[r * 64 + (((kk * 4 + quad) ^ (r & 7)) * 8)];
            }
            #pragma unroll
            for (int i = 0; i < 4; ++i)
                #pragma unroll
                for (int j = 0; j < 4; ++j)
                    acc[i][j] = __builtin_amdgcn_mfma_f32_16x16x32_bf16(a[i], b[j], acc[i][j], 0, 0, 0);
        }
        __syncthreads();
    }

    float bias4[4];
    #pragma unroll
    for (int j = 0; j < 4; ++j) bias4[j] = bias[col0 + n0w + j * 16 + l16];

    if (!POOL) {
        #pragma unroll
        for (int i = 0; i < 4; ++i) {
            #pragma unroll
            for (int r = 0; r < 4; ++r) {
                int m = row0 + m0w + i * 16 + quad * 4 + r;
                if (m < N_NODES) {
                    #pragma unroll
                    for (int j = 0; j < 4; ++j) {
                        float v = fmaxf(acc[i][j][r] + bias4[j], 0.f);
                        int c = col0 + n0w + j * 16 + l16;
                        outb[(size_t)m * OUTSTR + c] = f2b(v);
                        if (FP8OUT) outf8[(size_t)m * (OUTSTR / 2) + c] = f2f8(v);
                    }
                }
            }
        }
    } else {
        int gmin = batch[row0];
        int gmax = batch[min(row0 + 127, N_NODES - 1)];
        int span = gmax - gmin + 1;
        if (span == 1) {
            float s[4] = {0.f, 0.f, 0.f, 0.f};
            #pragma unroll
            for (int i = 0; i < 4; ++i) {
                #pragma unroll
                for (int r = 0; r < 4; ++r) {
                    int m = row0 + m0w + i * 16 + quad * 4 + r;
                    if (m < N_NODES) {
                        #pragma unroll
                        for (int j = 0; j < 4; ++j)
                            s[j] += fmaxf(acc[i][j][r] + bias4[j], 0.f);
                    }
                }
            }
            int slot = (wave & 1) * 4 + quad;
            #pragma unroll
            for (int j = 0; j < 4; ++j)
                pool2[slot * 128 + n0w + j * 16 + l16] = s[j];
            __syncthreads();
            if (tid < 128) {
                float v = 0.f;
                #pragma unroll
                for (int k = 0; k < 8; ++k) v += pool2[k * 128 + tid];
                atomicAdd(psum + (size_t)gmin * HID + col0 + tid, v);
            }
        } else if (span <= 8) {
            for (int i = tid; i < span * 128; i += 256) pool2[i] = 0.f;
            __syncthreads();
            float s[4] = {0.f, 0.f, 0.f, 0.f};
            int cg = -1;
            #pragma unroll
            for (int i = 0; i < 4; ++i) {
                #pragma unroll
                for (int r = 0; r < 4; ++r) {
                    int m = row0 + m0w + i * 16 + quad * 4 + r;
                    if (m < N_NODES) {
                        int g = batch[m] - gmin;
                        if (g != cg) {
                            if (cg >= 0) {
                                #pragma unroll
                                for (int j = 0; j < 4; ++j)
                                    atomicAdd(&pool2[cg * 128 + n0w + j * 16 + l16], s[j]);
                            }
                            cg = g;
                            s[0] = s[1] = s[2] = s[3] = 0.f;
                        }
                        #pragma unroll
                        for (int j = 0; j < 4; ++j)
                            s[j] += fmaxf(acc[i][j][r] + bias4[j], 0.f);
                    }
                }
            }
            if (cg >= 0) {
                #pragma unroll
                for (int j = 0; j < 4; ++j)
                    atomicAdd(&pool2[cg * 128 + n0w + j * 16 + l16], s[j]);
            }
            __syncthreads();
            for (int i = tid; i < span * 128; i += 256) {
                float v = pool2[i];
                if (v != 0.f)
                    atomicAdd(psum + (size_t)(gmin + (i >> 7)) * HID + col0 + (i & 127), v);
            }
        } else {
            #pragma unroll
            for (int i = 0; i < 4; ++i) {
                #pragma unroll
                for (int r = 0; r < 4; ++r) {
                    int m = row0 + m0w + i * 16 + quad * 4 + r;
                    if (m < N_NODES) {
                        int g = batch[m];
                        #pragma unroll
                        for (int j = 0; j < 4; ++j) {
                            float v = fmaxf(acc[i][j][r] + bias4[j], 0.f);
                            atomicAdd(psum + (size_t)g * HID + col0 + n0w + j * 16 + l16, v);
                        }
                    }
                }
            }
        }
    }
}

// ---------------- head (3-kernel split for parallelism) ----------------
__global__ __launch_bounds__(64) void head_hc_kernel(
    const float* __restrict__ psum, const float* __restrict__ ncnt,
    const float* __restrict__ Wh, const float* __restrict__ bh,
    const float* __restrict__ Wc, const float* __restrict__ bc,
    float* __restrict__ out)
{
    __shared__ float p[HID];
    const int tile = blockIdx.x, g = blockIdx.y, t = threadIdx.x;
    float inv = 1.0f / fmaxf(ncnt[g], 1.0f);
    #pragma unroll
    for (int i = 0; i < 8; ++i)
        p[i * 64 + t] = psum[(size_t)g * HID + i * 64 + t] * inv;
    __syncthreads();
    int col = tile * 64 + t;
    float h = bh[col], c = bc[col];
    #pragma unroll 8
    for (int k = 0; k < HID; ++k) {
        float pk = p[k];
        h += pk * Wh[(size_t)k * HID + col];
        c += pk * Wc[(size_t)k * HID + col];
    }
    out[(size_t)N_GRAPHS * VOCAB + (size_t)g * HID + col] = h;       // hidden
    out[(size_t)2 * N_GRAPHS * VOCAB + (size_t)g * HID + col] = c;   // cell
}

__global__ __launch_bounds__(64) void head_logits_kernel(
    const float* __restrict__ hidden, const float* __restrict__ Wout,
    const float* __restrict__ bout, float* __restrict__ lgt)
{
    __shared__ float hrow[HID];
    const int tile = blockIdx.x, g = blockIdx.y, t = threadIdx.x;
    #pragma unroll
    for (int i = 0; i < 8; ++i)
        hrow[i * 64 + t] = hidden[(size_t)g * HID + i * 64 + t];
    __syncthreads();
    int col = tile * 64 + t;
    float l = bout[col];
    #pragma unroll 8
    for (int k = 0; k < HID; ++k)
        l += hrow[k] * Wout[(size_t)k * VOCAB + col];
    lgt[(size_t)g * VOCAB + col] = l;
}

__global__ __launch_bounds__(512) void head_lsm_kernel(
    const float* __restrict__ lgt, float* __restrict__ out)
{
    __shared__ float redm[8];
    __shared__ float reds[8];
    __shared__ float bm, bs;
    const int g = blockIdx.x, j = threadIdx.x;
    float l = lgt[(size_t)g * VOCAB + j];
    const int lane = j & 63, wave = j >> 6;
    float m = l;
    #pragma unroll
    for (int o = 32; o > 0; o >>= 1) m = fmaxf(m, __shfl_down(m, o));
    if (lane == 0) redm[wave] = m;
    __syncthreads();
    if (j == 0) {
        float mm = redm[0];
        for (int w = 1; w < 8; ++w) mm = fmaxf(mm, redm[w]);
        bm = mm;
    }
    __syncthreads();
    m = bm;
    float e = __expf(l - m);
    float s = e;
    #pragma unroll
    for (int o = 32; o > 0; o >>= 1) s += __shfl_down(s, o);
    if (lane == 0) reds[wave] = s;
    __syncthreads();
    if (j == 0) {
        float ss = 0.f;
        for (int w = 0; w < 8; ++w) ss += reds[w];
        bs = ss;
    }
    __syncthreads();
    out[(size_t)g * VOCAB + j] = l - m - logf(bs);                  // logits
}

// ---------------- launch ----------------
extern "C" void kernel_launch(void* const* d_in, const int* in_sizes, int n_in,
                              void* d_out, int out_size, void* d_ws, size_t ws_size,
                              hipStream_t stream) {
    const float* x      = (const float*)d_in[1];
    const int*   edge   = (const int*)d_in[2];
    const int*   batch  = (const int*)d_in[3];
    const float* Wroot1 = (const float*)d_in[4];
    const float* Wrel1  = (const float*)d_in[5];
    const float* b1     = (const float*)d_in[6];
    const float* Wroot2 = (const float*)d_in[7];
    const float* Wrel2  = (const float*)d_in[8];
    const float* b2     = (const float*)d_in[9];
    const float* Wh     = (const float*)d_in[10];
    const float* bh     = (const float*)d_in[11];
    const float* Wc     = (const float*)d_in[12];
    const float* bc     = (const float*)d_in[13];
    const float* Wout   = (const float*)d_in[14];
    const float* bout   = (const float*)d_in[15];
    float* out = (float*)d_out;

    // workspace layout
    int*      deg_i   = (int*)d_ws;                        // 50000 (zeroed)
    int*      cursor  = deg_i + N_NODES;                   // 50000 (init by scan_final)
    float*    ncnt    = (float*)(cursor + N_NODES);        // 64
    float*    psum    = ncnt + N_GRAPHS;                   // 32768 (zeroed)
    int*      offsets = (int*)(psum + N_GRAPHS * HID);     // 50001
    int*      srcbuf  = offsets + (N_NODES + 1);           // 800000
    int*      bsum    = srcbuf + N_EDGES;                  // 256
    int*      bbase   = bsum + 256;                        // 256
    float*    rinv    = (float*)(bbase + 256);             // 50000 (+3 pad)
    ushort_t* xb      = (ushort_t*)(rinv + N_NODES + 3);   // 50000*256 bf16
    ushort_t* h1b     = xb + (size_t)N_NODES * 256;        // 50000*512 bf16
    ushort_t* w1t     = h1b + (size_t)N_NODES * 512;       // 256*256
    ushort_t* w2t     = w1t + 256 * 256;                   // 512*512
    uchar_t*  h1f8    = (uchar_t*)(w2t + 512 * 512);       // 50000*256 fp8
    float*    lgt     = (float*)(h1f8 + (size_t)N_NODES * 256); // 64*512 raw logits

    const size_t zero_bytes = (size_t)(2 * N_NODES + N_GRAPHS + N_GRAPHS * HID) * 4;
    hipMemsetAsync(d_ws, 0, zero_bytes, stream);

    deg_kernel<<<(N_EDGES + 255) / 256, 256, 0, stream>>>(edge, deg_i);
    scan_part_kernel<<<SCAN_NB, SCAN_B, 0, stream>>>(deg_i, bsum);
    scan_base_kernel<<<1, SCAN_B, 0, stream>>>(bsum, bbase, batch, ncnt);
    scan_final_kernel<<<SCAN_NB, SCAN_B, 0, stream>>>(deg_i, bbase, offsets, cursor, rinv);
    fill_kernel<<<(N_EDGES + 255) / 256, 256, 0, stream>>>(edge, cursor, srcbuf);

    conv_x_kernel<<<(N_NODES * 32) / 256, 256, 0, stream>>>(x, xb);
    conv_wt2_kernel<<<(256 * 256 + 512 * 512) / 256, 256, 0, stream>>>(
        Wroot1, Wrel1, Wroot2, Wrel2, w1t, w2t);

    gather1_kernel<<<(N_NODES + 3) / 4, 256, 0, stream>>>(offsets, srcbuf, rinv, xb);

    {   // layer 1: A=xb [50000 x 256] bf16 -> h1b cols 0..255 (+ fp8 copy); COLS=2
        mfma_gemm<256, 512, false, true, 2><<<8 * RPX * 2, 256, 0, stream>>>(
            xb, w1t, b1, h1b, h1f8, nullptr, nullptr);
    }

    gather2_kernel<<<(N_NODES + 3) / 4, 256, 0, stream>>>(offsets, srcbuf, rinv, h1f8, h1b);

    {   // layer 2: A=h1b [50000 x 512] bf16 -> pooled psum; COLS=4 (round-10 config)
        mfma_gemm<512, 512, true, false, 4><<<8 * RPX * 4, 256, 0, stream>>>(
            h1b, w2t, b2, nullptr, nullptr, psum, batch);
    }

    head_hc_kernel<<<dim3(8, 64), 64, 0, stream>>>(psum, ncnt, Wh, bh, Wc, bc, out);
    head_logits_kernel<<<dim3(8, 64), 64, 0, stream>>>(
        out + (size_t)N_GRAPHS * VOCAB, Wout, bout, lgt);
    head_lsm_kernel<<<N_GRAPHS, 512, 0, stream>>>(lgt, out);
}

// Round 13
// 412.346 us; speedup vs baseline: 1.0842x; 1.0842x over previous
//
#include <hip/hip_runtime.h>
#include <hip/hip_bf16.h>

#define N_NODES 50000
#define N_EDGES 800000
#define N_GRAPHS 64
#define FEAT 128
#define EMB 256
#define HID 512
#define VOCAB 512

#define SCAN_B 256
#define SCAN_NB ((N_NODES + SCAN_B - 1) / SCAN_B)   // 196
#define RB ((N_NODES + 127) / 128)                  // 391 row-blocks
#define RPX ((RB + 7) / 8)                          // 49 row-blocks per XCD
#define DRANGE ((N_NODES + 7) / 8)                  // 6250 dst per partition
#define EPT 8                                       // edges/thread in deg/fill
#define EPB (256 * EPT)                             // 2048 edges/block
#define NBF ((N_EDGES + EPB - 1) / EPB)             // 391 slices

typedef __attribute__((ext_vector_type(8))) short short8;
typedef __attribute__((ext_vector_type(4))) float floatx4;
typedef __attribute__((ext_vector_type(2))) float floatx2;
typedef unsigned short ushort_t;
typedef unsigned int uint32;
typedef unsigned char uchar_t;

__device__ __forceinline__ ushort_t f2b(float f) {
    uint32 u = __builtin_bit_cast(uint32, f);
    u += 0x7fffu + ((u >> 16) & 1u);
    return (ushort_t)(u >> 16);
}
__device__ __forceinline__ float b2f(ushort_t h) {
    uint32 u = ((uint32)h) << 16;
    return __builtin_bit_cast(float, u);
}
// u holds bf16 pair [even, odd]; accumulate into a (even) and b (odd)
__device__ __forceinline__ void acc2(uint32 u, float& a, float& b) {
    a += __builtin_bit_cast(float, u << 16);
    b += __builtin_bit_cast(float, u & 0xffff0000u);
}
// u holds 4 fp8 e4m3; accumulate into a[0..3]
__device__ __forceinline__ void accf8(uint32 u, float* a) {
    floatx2 lo = __builtin_amdgcn_cvt_pk_f32_fp8(u, false);
    floatx2 hi = __builtin_amdgcn_cvt_pk_f32_fp8(u, true);
    a[0] += lo[0]; a[1] += lo[1]; a[2] += hi[0]; a[3] += hi[1];
}
__device__ __forceinline__ uchar_t f2f8(float v) {
    return (uchar_t)(__builtin_amdgcn_cvt_pk_fp8_f32(v, v, 0, false) & 0xff);
}
__device__ __forceinline__ void async16(const void* g, void* l) {
    __builtin_amdgcn_global_load_lds(
        (const __attribute__((address_space(1))) void*)g,
        (__attribute__((address_space(3))) void*)l, 16, 0, 0);
}

// ---------------- CSR build (dst-range partitioned: group = blockIdx&7) ----------------
// Each group g handles dst in [g*DRANGE, (g+1)*DRANGE): its deg/cursor/srcbuf
// region stays in one XCD's L2 (blockIdx&7 round-robin ~ XCD), no line ping-pong.

__global__ void deg_kernel(const int* __restrict__ edge, int* __restrict__ deg) {
    int grp = blockIdx.x & 7;
    int slice = blockIdx.x >> 3;
    int dlo = grp * DRANGE;
    int dhi = min(dlo + DRANGE, N_NODES);
    int base = slice * EPB + threadIdx.x;
    #pragma unroll
    for (int i = 0; i < EPT; ++i) {
        int e = base + i * 256;
        if (e < N_EDGES) {
            int dst = edge[N_EDGES + e];
            if (dst >= dlo && dst < dhi) atomicAdd(deg + dst, 1);
        }
    }
}

__global__ void fill_kernel(const int* __restrict__ edge,
                            int* __restrict__ cursor, int* __restrict__ srcbuf) {
    int grp = blockIdx.x & 7;
    int slice = blockIdx.x >> 3;
    int dlo = grp * DRANGE;
    int dhi = min(dlo + DRANGE, N_NODES);
    int base = slice * EPB + threadIdx.x;
    #pragma unroll
    for (int i = 0; i < EPT; ++i) {
        int e = base + i * 256;
        if (e < N_EDGES) {
            int dst = edge[N_EDGES + e];
            if (dst >= dlo && dst < dhi) {
                int pos = atomicAdd(cursor + dst, 1);   // cursor pre-init to offsets
                srcbuf[pos] = edge[e];
            }
        }
    }
}

// ---- 3-phase parallel exclusive scan of deg -> offsets (+ fused rinv/cursor/ncnt) ----
__global__ __launch_bounds__(SCAN_B) void scan_part_kernel(const int* __restrict__ deg,
                                                           int* __restrict__ blocksum) {
    __shared__ int s[SCAN_B];
    int i = blockIdx.x * SCAN_B + threadIdx.x;
    int t = threadIdx.x;
    s[t] = (i < N_NODES) ? deg[i] : 0;
    __syncthreads();
    #pragma unroll
    for (int off = SCAN_B / 2; off > 0; off >>= 1) {
        if (t < off) s[t] += s[t + off];
        __syncthreads();
    }
    if (t == 0) blocksum[blockIdx.x] = s[0];
}

// scan of block sums + (threads 0..63) ncnt via binary search on sorted batch
__global__ __launch_bounds__(SCAN_B) void scan_base_kernel(const int* __restrict__ blocksum,
                                                           int* __restrict__ blockbase,
                                                           const int* __restrict__ batch,
                                                           float* __restrict__ ncnt) {
    __shared__ int s[SCAN_B];
    int t = threadIdx.x;
    int v = (t < SCAN_NB) ? blocksum[t] : 0;
    s[t] = v;
    __syncthreads();
    #pragma unroll
    for (int off = 1; off < SCAN_B; off <<= 1) {
        int u = (t >= off) ? s[t - off] : 0;
        __syncthreads();
        s[t] += u;
        __syncthreads();
    }
    blockbase[t] = s[t] - v;   // exclusive
    if (t < N_GRAPHS) {
        int g = t;
        int lo = 0, hi = N_NODES;
        while (lo < hi) { int mid = (lo + hi) >> 1; if (batch[mid] < g) lo = mid + 1; else hi = mid; }
        int lo2 = lo, hi2 = N_NODES;
        while (lo2 < hi2) { int mid = (lo2 + hi2) >> 1; if (batch[mid] < g + 1) lo2 = mid + 1; else hi2 = mid; }
        ncnt[g] = (float)(lo2 - lo);
    }
}

__global__ __launch_bounds__(SCAN_B) void scan_final_kernel(const int* __restrict__ deg,
                                                            const int* __restrict__ blockbase,
                                                            int* __restrict__ offsets,
                                                            int* __restrict__ cursor,
                                                            float* __restrict__ rinv) {
    __shared__ int s[SCAN_B];
    int i = blockIdx.x * SCAN_B + threadIdx.x;
    int t = threadIdx.x;
    int v = (i < N_NODES) ? deg[i] : 0;
    s[t] = v;
    __syncthreads();
    #pragma unroll
    for (int off = 1; off < SCAN_B; off <<= 1) {
        int u = (t >= off) ? s[t - off] : 0;
        __syncthreads();
        s[t] += u;
        __syncthreads();
    }
    int excl = s[t] - v + blockbase[blockIdx.x];
    if (i < N_NODES) {
        offsets[i] = excl;
        cursor[i] = excl;          // fill uses cursor directly (abs position)
        rinv[i] = 1.0f / (float)max(v, 1);
    }
    if (i == N_NODES - 1) offsets[N_NODES] = excl + v;
}

// ---------------- converts ----------------

__global__ void conv_x_kernel(const float* __restrict__ x, ushort_t* __restrict__ xb) {
    int tid = blockIdx.x * blockDim.x + threadIdx.x;   // N_NODES*32
    int row = tid >> 5, c = (tid & 31) * 4;
    float4 v = *(const float4*)(x + (size_t)row * FEAT + c);
    ushort4 o;
    o.x = f2b(v.x); o.y = f2b(v.y); o.z = f2b(v.z); o.w = f2b(v.w);
    *(ushort4*)(xb + (size_t)row * (2 * FEAT) + c) = o;
}

// both weight transposes in one launch
__global__ void conv_wt2_kernel(const float* __restrict__ W01, const float* __restrict__ W11,
                                const float* __restrict__ W02, const float* __restrict__ W12,
                                ushort_t* __restrict__ w1t, ushort_t* __restrict__ w2t) {
    int tid = blockIdx.x * blockDim.x + threadIdx.x;
    if (tid < 256 * 256) {
        int n = tid >> 8, k = tid & 255;
        float v = (k < 128) ? W01[(size_t)k * 256 + n] : W11[(size_t)(k - 128) * 256 + n];
        w1t[tid] = f2b(v);
    } else {
        int t2 = tid - 256 * 256;
        int n = t2 >> 9, k = t2 & 511;
        float v = (k < 256) ? W02[(size_t)k * 512 + n] : W12[(size_t)(k - 256) * 512 + n];
        w2t[t2] = f2b(v);
    }
}

// ---------------- CSR gathers ----------------
// gather1: bf16 source; 4 lane-groups of 16 handle 4 edges per instruction
__global__ __launch_bounds__(256) void gather1_kernel(
    const int* __restrict__ offsets, const int* __restrict__ srcbuf,
    const float* __restrict__ rinv, ushort_t* __restrict__ xb)
{
    int node = blockIdx.x * 4 + (threadIdx.x >> 6);
    if (node >= N_NODES) return;
    int lane = threadIdx.x & 63;
    int grp = lane >> 4;          // 0..3 (edge slot)
    int l16 = lane & 15;          // column group: cols l16*8 .. +7
    int beg = offsets[node], end = offsets[node + 1];

    float a[8] = {0.f, 0.f, 0.f, 0.f, 0.f, 0.f, 0.f, 0.f};
    int j = beg + grp;
    for (; j + 4 < end; j += 8) {
        int s0 = srcbuf[j];
        int s1 = srcbuf[j + 4];
        uint4 u0 = *(const uint4*)(xb + (size_t)s0 * 256 + l16 * 8);
        uint4 u1 = *(const uint4*)(xb + (size_t)s1 * 256 + l16 * 8);
        acc2(u0.x, a[0], a[1]); acc2(u0.y, a[2], a[3]);
        acc2(u0.z, a[4], a[5]); acc2(u0.w, a[6], a[7]);
        acc2(u1.x, a[0], a[1]); acc2(u1.y, a[2], a[3]);
        acc2(u1.z, a[4], a[5]); acc2(u1.w, a[6], a[7]);
    }
    for (; j < end; j += 4) {
        int s0 = srcbuf[j];
        uint4 u0 = *(const uint4*)(xb + (size_t)s0 * 256 + l16 * 8);
        acc2(u0.x, a[0], a[1]); acc2(u0.y, a[2], a[3]);
        acc2(u0.z, a[4], a[5]); acc2(u0.w, a[6], a[7]);
    }
    #pragma unroll
    for (int k = 0; k < 8; ++k) a[k] += __shfl_down(a[k], 32);
    #pragma unroll
    for (int k = 0; k < 8; ++k) a[k] += __shfl_down(a[k], 16);
    if (grp == 0) {
        float ri = rinv[node];
        uint4 o;
        o.x = (uint32)f2b(a[0] * ri) | ((uint32)f2b(a[1] * ri) << 16);
        o.y = (uint32)f2b(a[2] * ri) | ((uint32)f2b(a[3] * ri) << 16);
        o.z = (uint32)f2b(a[4] * ri) | ((uint32)f2b(a[5] * ri) << 16);
        o.w = (uint32)f2b(a[6] * ri) | ((uint32)f2b(a[7] * ri) << 16);
        *(uint4*)(xb + (size_t)node * 256 + 128 + l16 * 8) = o;
    }
}

// gather2: fp8 source (256 B/row); 4 lane-groups of 16, lane covers 16 cols
__global__ __launch_bounds__(256) void gather2_kernel(
    const int* __restrict__ offsets, const int* __restrict__ srcbuf,
    const float* __restrict__ rinv, const uchar_t* __restrict__ h1f8,
    ushort_t* __restrict__ h1b)
{
    int node = blockIdx.x * 4 + (threadIdx.x >> 6);
    if (node >= N_NODES) return;
    int lane = threadIdx.x & 63;
    int grp = lane >> 4;          // 0..3 (edge slot)
    int l16 = lane & 15;          // cols l16*16 .. +15
    int beg = offsets[node], end = offsets[node + 1];

    float a[16];
    #pragma unroll
    for (int k = 0; k < 16; ++k) a[k] = 0.f;

    int j = beg + grp;
    for (; j + 4 < end; j += 8) {
        int s0 = srcbuf[j];
        int s1 = srcbuf[j + 4];
        uint4 u0 = *(const uint4*)(h1f8 + (size_t)s0 * 256 + l16 * 16);
        uint4 u1 = *(const uint4*)(h1f8 + (size_t)s1 * 256 + l16 * 16);
        accf8(u0.x, a + 0); accf8(u0.y, a + 4); accf8(u0.z, a + 8); accf8(u0.w, a + 12);
        accf8(u1.x, a + 0); accf8(u1.y, a + 4); accf8(u1.z, a + 8); accf8(u1.w, a + 12);
    }
    for (; j < end; j += 4) {
        int s0 = srcbuf[j];
        uint4 u0 = *(const uint4*)(h1f8 + (size_t)s0 * 256 + l16 * 16);
        accf8(u0.x, a + 0); accf8(u0.y, a + 4); accf8(u0.z, a + 8); accf8(u0.w, a + 12);
    }
    #pragma unroll
    for (int k = 0; k < 16; ++k) a[k] += __shfl_down(a[k], 32);
    #pragma unroll
    for (int k = 0; k < 16; ++k) a[k] += __shfl_down(a[k], 16);
    if (grp == 0) {
        float ri = rinv[node];
        uint4 o0, o1;
        o0.x = (uint32)f2b(a[0] * ri)  | ((uint32)f2b(a[1] * ri) << 16);
        o0.y = (uint32)f2b(a[2] * ri)  | ((uint32)f2b(a[3] * ri) << 16);
        o0.z = (uint32)f2b(a[4] * ri)  | ((uint32)f2b(a[5] * ri) << 16);
        o0.w = (uint32)f2b(a[6] * ri)  | ((uint32)f2b(a[7] * ri) << 16);
        o1.x = (uint32)f2b(a[8] * ri)  | ((uint32)f2b(a[9] * ri) << 16);
        o1.y = (uint32)f2b(a[10] * ri) | ((uint32)f2b(a[11] * ri) << 16);
        o1.z = (uint32)f2b(a[12] * ri) | ((uint32)f2b(a[13] * ri) << 16);
        o1.w = (uint32)f2b(a[14] * ri) | ((uint32)f2b(a[15] * ri) << 16);
        *(uint4*)(h1b + (size_t)node * 512 + 256 + l16 * 16) = o0;
        *(uint4*)(h1b + (size_t)node * 512 + 256 + l16 * 16 + 8) = o1;
    }
}

// ---------------- bf16 MFMA GEMM (128x128 tile, BK=64, XCD-swizzled dispatch) ----------------
template<int KTOT, int OUTSTR, bool POOL, bool FP8OUT, int COLS>
__global__ __launch_bounds__(256) void mfma_gemm(
    const ushort_t* __restrict__ A, const ushort_t* __restrict__ Bt,
    const float* __restrict__ bias,
    ushort_t* __restrict__ outb, uchar_t* __restrict__ outf8,
    float* __restrict__ psum, const int* __restrict__ batch)
{
    __shared__ ushort_t As[8192];       // 128 x 64 k, 16 KB
    __shared__ ushort_t Bs[8192];       // 128 x 64 k, 16 KB
    __shared__ float pool2[8 * 128];    // POOL reduction scratch (4 KB)

    const int id = blockIdx.x;
    const int xcd = id & 7;
    const int s_ = id >> 3;
    const int col = s_ & (COLS - 1);
    const int rloc = s_ / COLS;
    const int rowblk = xcd * RPX + rloc;
    if (rowblk >= RB) return;

    const int tid = threadIdx.x;
    const int lane = tid & 63;
    const int wave = tid >> 6;
    const int quad = lane >> 4;
    const int l16 = lane & 15;
    const int m0w = (wave & 1) * 64;
    const int n0w = (wave >> 1) * 64;
    const int row0 = rowblk * 128;
    const int col0 = col * 128;
    const int Mm1 = N_NODES - 1;

    int st_r[4], st_q[4];
    #pragma unroll
    for (int c = 0; c < 4; ++c) {
        int slot = c * 256 + tid;
        int r = slot >> 3;
        st_r[c] = r;
        st_q[c] = ((slot & 7) ^ (r & 7)) * 8;
    }

    floatx4 acc[4][4] = {};

    for (int kt = 0; kt < KTOT / 64; ++kt) {
        const int kb = kt * 64;
        #pragma unroll
        for (int c = 0; c < 4; ++c) {
            async16(A + (size_t)min(row0 + st_r[c], Mm1) * KTOT + kb + st_q[c],
                    &As[(c * 256 + wave * 64) * 8]);
        }
        #pragma unroll
        for (int c = 0; c < 4; ++c) {
            async16(Bt + (size_t)(col0 + st_r[c]) * KTOT + kb + st_q[c],
                    &Bs[(c * 256 + wave * 64) * 8]);
        }
        __syncthreads();
        #pragma unroll
        for (int kk = 0; kk < 2; ++kk) {
            short8 a[4], b[4];
            #pragma unroll
            for (int t = 0; t < 4; ++t) {
                int r = m0w + t * 16 + l16;
                a[t] = *(const short8*)&As[r * 64 + (((kk * 4 + quad) ^ (r & 7)) * 8)];
            }
            #pragma unroll
            for (int t = 0; t < 4; ++t) {
                int r = n0w + t * 16 + l16;
                b[t] = *(const short8*)&Bs[r * 64 + (((kk * 4 + quad) ^ (r & 7)) * 8)];
            }
            #pragma unroll
            for (int i = 0; i < 4; ++i)
                #pragma unroll
                for (int j = 0; j < 4; ++j)
                    acc[i][j] = __builtin_amdgcn_mfma_f32_16x16x32_bf16(a[i], b[j], acc[i][j], 0, 0, 0);
        }
        __syncthreads();
    }

    float bias4[4];
    #pragma unroll
    for (int j = 0; j < 4; ++j) bias4[j] = bias[col0 + n0w + j * 16 + l16];

    if (!POOL) {
        #pragma unroll
        for (int i = 0; i < 4; ++i) {
            #pragma unroll
            for (int r = 0; r < 4; ++r) {
                int m = row0 + m0w + i * 16 + quad * 4 + r;
                if (m < N_NODES) {
                    #pragma unroll
                    for (int j = 0; j < 4; ++j) {
                        float v = fmaxf(acc[i][j][r] + bias4[j], 0.f);
                        int c = col0 + n0w + j * 16 + l16;
                        outb[(size_t)m * OUTSTR + c] = f2b(v);
                        if (FP8OUT) outf8[(size_t)m * (OUTSTR / 2) + c] = f2f8(v);
                    }
                }
            }
        }
    } else {
        int gmin = batch[row0];
        int gmax = batch[min(row0 + 127, N_NODES - 1)];
        int span = gmax - gmin + 1;
        if (span == 1) {
            float s[4] = {0.f, 0.f, 0.f, 0.f};
            #pragma unroll
            for (int i = 0; i < 4; ++i) {
                #pragma unroll
                for (int r = 0; r < 4; ++r) {
                    int m = row0 + m0w + i * 16 + quad * 4 + r;
                    if (m < N_NODES) {
                        #pragma unroll
                        for (int j = 0; j < 4; ++j)
                            s[j] += fmaxf(acc[i][j][r] + bias4[j], 0.f);
                    }
                }
            }
            int slot = (wave & 1) * 4 + quad;
            #pragma unroll
            for (int j = 0; j < 4; ++j)
                pool2[slot * 128 + n0w + j * 16 + l16] = s[j];
            __syncthreads();
            if (tid < 128) {
                float v = 0.f;
                #pragma unroll
                for (int k = 0; k < 8; ++k) v += pool2[k * 128 + tid];
                atomicAdd(psum + (size_t)gmin * HID + col0 + tid, v);
            }
        } else if (span <= 8) {
            for (int i = tid; i < span * 128; i += 256) pool2[i] = 0.f;
            __syncthreads();
            float s[4] = {0.f, 0.f, 0.f, 0.f};
            int cg = -1;
            #pragma unroll
            for (int i = 0; i < 4; ++i) {
                #pragma unroll
                for (int r = 0; r < 4; ++r) {
                    int m = row0 + m0w + i * 16 + quad * 4 + r;
                    if (m < N_NODES) {
                        int g = batch[m] - gmin;
                        if (g != cg) {
                            if (cg >= 0) {
                                #pragma unroll
                                for (int j = 0; j < 4; ++j)
                                    atomicAdd(&pool2[cg * 128 + n0w + j * 16 + l16], s[j]);
                            }
                            cg = g;
                            s[0] = s[1] = s[2] = s[3] = 0.f;
                        }
                        #pragma unroll
                        for (int j = 0; j < 4; ++j)
                            s[j] += fmaxf(acc[i][j][r] + bias4[j], 0.f);
                    }
                }
            }
            if (cg >= 0) {
                #pragma unroll
                for (int j = 0; j < 4; ++j)
                    atomicAdd(&pool2[cg * 128 + n0w + j * 16 + l16], s[j]);
            }
            __syncthreads();
            for (int i = tid; i < span * 128; i += 256) {
                float v = pool2[i];
                if (v != 0.f)
                    atomicAdd(psum + (size_t)(gmin + (i >> 7)) * HID + col0 + (i & 127), v);
            }
        } else {
            #pragma unroll
            for (int i = 0; i < 4; ++i) {
                #pragma unroll
                for (int r = 0; r < 4; ++r) {
                    int m = row0 + m0w + i * 16 + quad * 4 + r;
                    if (m < N_NODES) {
                        int g = batch[m];
                        #pragma unroll
                        for (int j = 0; j < 4; ++j) {
                            float v = fmaxf(acc[i][j][r] + bias4[j], 0.f);
                            atomicAdd(psum + (size_t)g * HID + col0 + n0w + j * 16 + l16, v);
                        }
                    }
                }
            }
        }
    }
}

// ---------------- head (3-kernel split for parallelism) ----------------
__global__ __launch_bounds__(64) void head_hc_kernel(
    const float* __restrict__ psum, const float* __restrict__ ncnt,
    const float* __restrict__ Wh, const float* __restrict__ bh,
    const float* __restrict__ Wc, const float* __restrict__ bc,
    float* __restrict__ out)
{
    __shared__ float p[HID];
    const int tile = blockIdx.x, g = blockIdx.y, t = threadIdx.x;
    float inv = 1.0f / fmaxf(ncnt[g], 1.0f);
    #pragma unroll
    for (int i = 0; i < 8; ++i)
        p[i * 64 + t] = psum[(size_t)g * HID + i * 64 + t] * inv;
    __syncthreads();
    int col = tile * 64 + t;
    float h = bh[col], c = bc[col];
    #pragma unroll 8
    for (int k = 0; k < HID; ++k) {
        float pk = p[k];
        h += pk * Wh[(size_t)k * HID + col];
        c += pk * Wc[(size_t)k * HID + col];
    }
    out[(size_t)N_GRAPHS * VOCAB + (size_t)g * HID + col] = h;       // hidden
    out[(size_t)2 * N_GRAPHS * VOCAB + (size_t)g * HID + col] = c;   // cell
}

__global__ __launch_bounds__(64) void head_logits_kernel(
    const float* __restrict__ hidden, const float* __restrict__ Wout,
    const float* __restrict__ bout, float* __restrict__ lgt)
{
    __shared__ float hrow[HID];
    const int tile = blockIdx.x, g = blockIdx.y, t = threadIdx.x;
    #pragma unroll
    for (int i = 0; i < 8; ++i)
        hrow[i * 64 + t] = hidden[(size_t)g * HID + i * 64 + t];
    __syncthreads();
    int col = tile * 64 + t;
    float l = bout[col];
    #pragma unroll 8
    for (int k = 0; k < HID; ++k)
        l += hrow[k] * Wout[(size_t)k * VOCAB + col];
    lgt[(size_t)g * VOCAB + col] = l;
}

__global__ __launch_bounds__(512) void head_lsm_kernel(
    const float* __restrict__ lgt, float* __restrict__ out)
{
    __shared__ float redm[8];
    __shared__ float reds[8];
    __shared__ float bm, bs;
    const int g = blockIdx.x, j = threadIdx.x;
    float l = lgt[(size_t)g * VOCAB + j];
    const int lane = j & 63, wave = j >> 6;
    float m = l;
    #pragma unroll
    for (int o = 32; o > 0; o >>= 1) m = fmaxf(m, __shfl_down(m, o));
    if (lane == 0) redm[wave] = m;
    __syncthreads();
    if (j == 0) {
        float mm = redm[0];
        for (int w = 1; w < 8; ++w) mm = fmaxf(mm, redm[w]);
        bm = mm;
    }
    __syncthreads();
    m = bm;
    float e = __expf(l - m);
    float s = e;
    #pragma unroll
    for (int o = 32; o > 0; o >>= 1) s += __shfl_down(s, o);
    if (lane == 0) reds[wave] = s;
    __syncthreads();
    if (j == 0) {
        float ss = 0.f;
        for (int w = 0; w < 8; ++w) ss += reds[w];
        bs = ss;
    }
    __syncthreads();
    out[(size_t)g * VOCAB + j] = l - m - logf(bs);                  // logits
}

// ---------------- launch ----------------
extern "C" void kernel_launch(void* const* d_in, const int* in_sizes, int n_in,
                              void* d_out, int out_size, void* d_ws, size_t ws_size,
                              hipStream_t stream) {
    const float* x      = (const float*)d_in[1];
    const int*   edge   = (const int*)d_in[2];
    const int*   batch  = (const int*)d_in[3];
    const float* Wroot1 = (const float*)d_in[4];
    const float* Wrel1  = (const float*)d_in[5];
    const float* b1     = (const float*)d_in[6];
    const float* Wroot2 = (const float*)d_in[7];
    const float* Wrel2  = (const float*)d_in[8];
    const float* b2     = (const float*)d_in[9];
    const float* Wh     = (const float*)d_in[10];
    const float* bh     = (const float*)d_in[11];
    const float* Wc     = (const float*)d_in[12];
    const float* bc     = (const float*)d_in[13];
    const float* Wout   = (const float*)d_in[14];
    const float* bout   = (const float*)d_in[15];
    float* out = (float*)d_out;

    // workspace layout
    int*      deg_i   = (int*)d_ws;                        // 50000 (zeroed)
    int*      cursor  = deg_i + N_NODES;                   // 50000 (init by scan_final)
    float*    ncnt    = (float*)(cursor + N_NODES);        // 64
    float*    psum    = ncnt + N_GRAPHS;                   // 32768 (zeroed)
    int*      offsets = (int*)(psum + N_GRAPHS * HID);     // 50001
    int*      srcbuf  = offsets + (N_NODES + 1);           // 800000
    int*      bsum    = srcbuf + N_EDGES;                  // 256
    int*      bbase   = bsum + 256;                        // 256
    float*    rinv    = (float*)(bbase + 256);             // 50000 (+3 pad)
    ushort_t* xb      = (ushort_t*)(rinv + N_NODES + 3);   // 50000*256 bf16
    ushort_t* h1b     = xb + (size_t)N_NODES * 256;        // 50000*512 bf16
    ushort_t* w1t     = h1b + (size_t)N_NODES * 512;       // 256*256
    ushort_t* w2t     = w1t + 256 * 256;                   // 512*512
    uchar_t*  h1f8    = (uchar_t*)(w2t + 512 * 512);       // 50000*256 fp8
    float*    lgt     = (float*)(h1f8 + (size_t)N_NODES * 256); // 64*512 raw logits

    // zero deg + psum region (cursor zeroed too, harmless; scan_final overwrites)
    const size_t zero_bytes = (size_t)(2 * N_NODES + N_GRAPHS + N_GRAPHS * HID) * 4;
    hipMemsetAsync(d_ws, 0, zero_bytes, stream);

    deg_kernel<<<8 * NBF, 256, 0, stream>>>(edge, deg_i);
    scan_part_kernel<<<SCAN_NB, SCAN_B, 0, stream>>>(deg_i, bsum);
    scan_base_kernel<<<1, SCAN_B, 0, stream>>>(bsum, bbase, batch, ncnt);
    scan_final_kernel<<<SCAN_NB, SCAN_B, 0, stream>>>(deg_i, bbase, offsets, cursor, rinv);
    fill_kernel<<<8 * NBF, 256, 0, stream>>>(edge, cursor, srcbuf);

    conv_x_kernel<<<(N_NODES * 32) / 256, 256, 0, stream>>>(x, xb);
    conv_wt2_kernel<<<(256 * 256 + 512 * 512) / 256, 256, 0, stream>>>(
        Wroot1, Wrel1, Wroot2, Wrel2, w1t, w2t);

    gather1_kernel<<<(N_NODES + 3) / 4, 256, 0, stream>>>(offsets, srcbuf, rinv, xb);

    {   // layer 1: A=xb [50000 x 256] bf16 -> h1b cols 0..255 (+ fp8 copy); COLS=2
        mfma_gemm<256, 512, false, true, 2><<<8 * RPX * 2, 256, 0, stream>>>(
            xb, w1t, b1, h1b, h1f8, nullptr, nullptr);
    }

    gather2_kernel<<<(N_NODES + 3) / 4, 256, 0, stream>>>(offsets, srcbuf, rinv, h1f8, h1b);

    {   // layer 2: A=h1b [50000 x 512] bf16 -> pooled psum; COLS=4
        mfma_gemm<512, 512, true, false, 4><<<8 * RPX * 4, 256, 0, stream>>>(
            h1b, w2t, b2, nullptr, nullptr, psum, batch);
    }

    head_hc_kernel<<<dim3(8, 64), 64, 0, stream>>>(psum, ncnt, Wh, bh, Wc, bc, out);
    head_logits_kernel<<<dim3(8, 64), 64, 0, stream>>>(
        out + (size_t)N_GRAPHS * VOCAB, Wout, bout, lgt);
    head_lsm_kernel<<<N_GRAPHS, 512, 0, stream>>>(lgt, out);
}

// Round 14
// 404.545 us; speedup vs baseline: 1.1051x; 1.0193x over previous
//
#include <hip/hip_runtime.h>
#include <hip/hip_bf16.h>

#define N_NODES 50000
#define N_EDGES 800000
#define N_GRAPHS 64
#define FEAT 128
#define EMB 256
#define HID 512
#define VOCAB 512

#define SCAN_B 256
#define SCAN_NB ((N_NODES + SCAN_B - 1) / SCAN_B)   // 196
#define RB ((N_NODES + 127) / 128)                  // 391 row-blocks
#define RPX ((RB + 7) / 8)                          // 49 row-blocks per XCD
#define DRANGE ((N_NODES + 7) / 8)                  // 6250 dst per partition
#define EPT 8                                       // edges/thread in deg/fill
#define EPB (256 * EPT)                             // 2048 edges/block
#define NBF ((N_EDGES + EPB - 1) / EPB)             // 391 slices

typedef __attribute__((ext_vector_type(8))) short short8;
typedef __attribute__((ext_vector_type(4))) float floatx4;
typedef __attribute__((ext_vector_type(2))) float floatx2;
typedef unsigned short ushort_t;
typedef unsigned int uint32;
typedef unsigned char uchar_t;

__device__ __forceinline__ ushort_t f2b(float f) {
    uint32 u = __builtin_bit_cast(uint32, f);
    u += 0x7fffu + ((u >> 16) & 1u);
    return (ushort_t)(u >> 16);
}
__device__ __forceinline__ float b2f(ushort_t h) {
    uint32 u = ((uint32)h) << 16;
    return __builtin_bit_cast(float, u);
}
// u holds bf16 pair [even, odd]; accumulate into a (even) and b (odd)
__device__ __forceinline__ void acc2(uint32 u, float& a, float& b) {
    a += __builtin_bit_cast(float, u << 16);
    b += __builtin_bit_cast(float, u & 0xffff0000u);
}
// u holds 4 fp8 e4m3; accumulate into a[0..3]
__device__ __forceinline__ void accf8(uint32 u, float* a) {
    floatx2 lo = __builtin_amdgcn_cvt_pk_f32_fp8(u, false);
    floatx2 hi = __builtin_amdgcn_cvt_pk_f32_fp8(u, true);
    a[0] += lo[0]; a[1] += lo[1]; a[2] += hi[0]; a[3] += hi[1];
}
__device__ __forceinline__ uchar_t f2f8(float v) {
    return (uchar_t)(__builtin_amdgcn_cvt_pk_fp8_f32(v, v, 0, false) & 0xff);
}
__device__ __forceinline__ void async16(const void* g, void* l) {
    __builtin_amdgcn_global_load_lds(
        (const __attribute__((address_space(1))) void*)g,
        (__attribute__((address_space(3))) void*)l, 16, 0, 0);
}

// ---------------- CSR build (dst-range partitioned: group = blockIdx&7) ----------------

__global__ void deg_kernel(const int* __restrict__ edge, int* __restrict__ deg) {
    int grp = blockIdx.x & 7;
    int slice = blockIdx.x >> 3;
    int dlo = grp * DRANGE;
    int dhi = min(dlo + DRANGE, N_NODES);
    int base = slice * EPB + threadIdx.x;
    #pragma unroll
    for (int i = 0; i < EPT; ++i) {
        int e = base + i * 256;
        if (e < N_EDGES) {
            int dst = edge[N_EDGES + e];
            if (dst >= dlo && dst < dhi) atomicAdd(deg + dst, 1);
        }
    }
}

__global__ void fill_kernel(const int* __restrict__ edge,
                            int* __restrict__ cursor, int* __restrict__ srcbuf) {
    int grp = blockIdx.x & 7;
    int slice = blockIdx.x >> 3;
    int dlo = grp * DRANGE;
    int dhi = min(dlo + DRANGE, N_NODES);
    int base = slice * EPB + threadIdx.x;
    #pragma unroll
    for (int i = 0; i < EPT; ++i) {
        int e = base + i * 256;
        if (e < N_EDGES) {
            int dst = edge[N_EDGES + e];
            if (dst >= dlo && dst < dhi) {
                int pos = atomicAdd(cursor + dst, 1);   // cursor pre-init to offsets
                srcbuf[pos] = edge[e];
            }
        }
    }
}

// ---- 3-phase parallel exclusive scan of deg -> offsets (+ fused rinv/cursor/ncnt) ----
__global__ __launch_bounds__(SCAN_B) void scan_part_kernel(const int* __restrict__ deg,
                                                           int* __restrict__ blocksum) {
    __shared__ int s[SCAN_B];
    int i = blockIdx.x * SCAN_B + threadIdx.x;
    int t = threadIdx.x;
    s[t] = (i < N_NODES) ? deg[i] : 0;
    __syncthreads();
    #pragma unroll
    for (int off = SCAN_B / 2; off > 0; off >>= 1) {
        if (t < off) s[t] += s[t + off];
        __syncthreads();
    }
    if (t == 0) blocksum[blockIdx.x] = s[0];
}

__global__ __launch_bounds__(SCAN_B) void scan_base_kernel(const int* __restrict__ blocksum,
                                                           int* __restrict__ blockbase,
                                                           const int* __restrict__ batch,
                                                           float* __restrict__ ncnt) {
    __shared__ int s[SCAN_B];
    int t = threadIdx.x;
    int v = (t < SCAN_NB) ? blocksum[t] : 0;
    s[t] = v;
    __syncthreads();
    #pragma unroll
    for (int off = 1; off < SCAN_B; off <<= 1) {
        int u = (t >= off) ? s[t - off] : 0;
        __syncthreads();
        s[t] += u;
        __syncthreads();
    }
    blockbase[t] = s[t] - v;   // exclusive
    if (t < N_GRAPHS) {
        int g = t;
        int lo = 0, hi = N_NODES;
        while (lo < hi) { int mid = (lo + hi) >> 1; if (batch[mid] < g) lo = mid + 1; else hi = mid; }
        int lo2 = lo, hi2 = N_NODES;
        while (lo2 < hi2) { int mid = (lo2 + hi2) >> 1; if (batch[mid] < g + 1) lo2 = mid + 1; else hi2 = mid; }
        ncnt[g] = (float)(lo2 - lo);
    }
}

__global__ __launch_bounds__(SCAN_B) void scan_final_kernel(const int* __restrict__ deg,
                                                            const int* __restrict__ blockbase,
                                                            int* __restrict__ offsets,
                                                            int* __restrict__ cursor,
                                                            float* __restrict__ rinv) {
    __shared__ int s[SCAN_B];
    int i = blockIdx.x * SCAN_B + threadIdx.x;
    int t = threadIdx.x;
    int v = (i < N_NODES) ? deg[i] : 0;
    s[t] = v;
    __syncthreads();
    #pragma unroll
    for (int off = 1; off < SCAN_B; off <<= 1) {
        int u = (t >= off) ? s[t - off] : 0;
        __syncthreads();
        s[t] += u;
        __syncthreads();
    }
    int excl = s[t] - v + blockbase[blockIdx.x];
    if (i < N_NODES) {
        offsets[i] = excl;
        cursor[i] = excl;
        rinv[i] = 1.0f / (float)max(v, 1);
    }
    if (i == N_NODES - 1) offsets[N_NODES] = excl + v;
}

// ---------------- fused converts: x->(bf16,fp8) + both weight transposes ----------------
__global__ void conv_all_kernel(const float* __restrict__ x,
                                const float* __restrict__ W01, const float* __restrict__ W11,
                                const float* __restrict__ W02, const float* __restrict__ W12,
                                ushort_t* __restrict__ xb, uchar_t* __restrict__ xf8,
                                ushort_t* __restrict__ w1t, ushort_t* __restrict__ w2t) {
    int tid = blockIdx.x * blockDim.x + threadIdx.x;
    if (tid < N_NODES * 32) {
        int row = tid >> 5, c = (tid & 31) * 4;
        float4 v = *(const float4*)(x + (size_t)row * FEAT + c);
        ushort4 o;
        o.x = f2b(v.x); o.y = f2b(v.y); o.z = f2b(v.z); o.w = f2b(v.w);
        *(ushort4*)(xb + (size_t)row * (2 * FEAT) + c) = o;
        uint32 p = __builtin_amdgcn_cvt_pk_fp8_f32(v.x, v.y, 0, false);
        p = __builtin_amdgcn_cvt_pk_fp8_f32(v.z, v.w, p, true);
        *(uint32*)(xf8 + (size_t)row * FEAT + c) = p;
    } else if (tid < N_NODES * 32 + 256 * 256) {
        int t1 = tid - N_NODES * 32;
        int n = t1 >> 8, k = t1 & 255;
        float v = (k < 128) ? W01[(size_t)k * 256 + n] : W11[(size_t)(k - 128) * 256 + n];
        w1t[t1] = f2b(v);
    } else {
        int t2 = tid - N_NODES * 32 - 256 * 256;
        int n = t2 >> 9, k = t2 & 511;
        float v = (k < 256) ? W02[(size_t)k * 512 + n] : W12[(size_t)(k - 256) * 512 + n];
        w2t[t2] = f2b(v);
    }
}

// ---------------- CSR gathers ----------------
// gather1: fp8 source (128 B/row); 8 lane-groups of 8 -> 8 edges per instruction
__global__ __launch_bounds__(256) void gather1_kernel(
    const int* __restrict__ offsets, const int* __restrict__ srcbuf,
    const float* __restrict__ rinv, const uchar_t* __restrict__ xf8,
    ushort_t* __restrict__ xb)
{
    int node = blockIdx.x * 4 + (threadIdx.x >> 6);
    if (node >= N_NODES) return;
    int lane = threadIdx.x & 63;
    int grp = lane >> 3;          // 0..7 (edge slot)
    int l8 = lane & 7;            // cols l8*16 .. +15
    int beg = offsets[node], end = offsets[node + 1];

    float a[16];
    #pragma unroll
    for (int k = 0; k < 16; ++k) a[k] = 0.f;

    int j = beg + grp;
    for (; j + 8 < end; j += 16) {
        int s0 = srcbuf[j];
        int s1 = srcbuf[j + 8];
        uint4 u0 = *(const uint4*)(xf8 + (size_t)s0 * FEAT + l8 * 16);
        uint4 u1 = *(const uint4*)(xf8 + (size_t)s1 * FEAT + l8 * 16);
        accf8(u0.x, a + 0); accf8(u0.y, a + 4); accf8(u0.z, a + 8); accf8(u0.w, a + 12);
        accf8(u1.x, a + 0); accf8(u1.y, a + 4); accf8(u1.z, a + 8); accf8(u1.w, a + 12);
    }
    for (; j < end; j += 8) {
        int s0 = srcbuf[j];
        uint4 u0 = *(const uint4*)(xf8 + (size_t)s0 * FEAT + l8 * 16);
        accf8(u0.x, a + 0); accf8(u0.y, a + 4); accf8(u0.z, a + 8); accf8(u0.w, a + 12);
    }
    #pragma unroll
    for (int k = 0; k < 16; ++k) a[k] += __shfl_down(a[k], 32);
    #pragma unroll
    for (int k = 0; k < 16; ++k) a[k] += __shfl_down(a[k], 16);
    #pragma unroll
    for (int k = 0; k < 16; ++k) a[k] += __shfl_down(a[k], 8);
    if (grp == 0) {
        float ri = rinv[node];
        uint4 o0, o1;
        o0.x = (uint32)f2b(a[0] * ri)  | ((uint32)f2b(a[1] * ri) << 16);
        o0.y = (uint32)f2b(a[2] * ri)  | ((uint32)f2b(a[3] * ri) << 16);
        o0.z = (uint32)f2b(a[4] * ri)  | ((uint32)f2b(a[5] * ri) << 16);
        o0.w = (uint32)f2b(a[6] * ri)  | ((uint32)f2b(a[7] * ri) << 16);
        o1.x = (uint32)f2b(a[8] * ri)  | ((uint32)f2b(a[9] * ri) << 16);
        o1.y = (uint32)f2b(a[10] * ri) | ((uint32)f2b(a[11] * ri) << 16);
        o1.z = (uint32)f2b(a[12] * ri) | ((uint32)f2b(a[13] * ri) << 16);
        o1.w = (uint32)f2b(a[14] * ri) | ((uint32)f2b(a[15] * ri) << 16);
        *(uint4*)(xb + (size_t)node * 256 + 128 + l8 * 16) = o0;
        *(uint4*)(xb + (size_t)node * 256 + 128 + l8 * 16 + 8) = o1;
    }
}

// gather2: fp8 source (256 B/row); 4 lane-groups of 16, lane covers 16 cols
__global__ __launch_bounds__(256) void gather2_kernel(
    const int* __restrict__ offsets, const int* __restrict__ srcbuf,
    const float* __restrict__ rinv, const uchar_t* __restrict__ h1f8,
    ushort_t* __restrict__ h1b)
{
    int node = blockIdx.x * 4 + (threadIdx.x >> 6);
    if (node >= N_NODES) return;
    int lane = threadIdx.x & 63;
    int grp = lane >> 4;          // 0..3 (edge slot)
    int l16 = lane & 15;          // cols l16*16 .. +15
    int beg = offsets[node], end = offsets[node + 1];

    float a[16];
    #pragma unroll
    for (int k = 0; k < 16; ++k) a[k] = 0.f;

    int j = beg + grp;
    for (; j + 4 < end; j += 8) {
        int s0 = srcbuf[j];
        int s1 = srcbuf[j + 4];
        uint4 u0 = *(const uint4*)(h1f8 + (size_t)s0 * 256 + l16 * 16);
        uint4 u1 = *(const uint4*)(h1f8 + (size_t)s1 * 256 + l16 * 16);
        accf8(u0.x, a + 0); accf8(u0.y, a + 4); accf8(u0.z, a + 8); accf8(u0.w, a + 12);
        accf8(u1.x, a + 0); accf8(u1.y, a + 4); accf8(u1.z, a + 8); accf8(u1.w, a + 12);
    }
    for (; j < end; j += 4) {
        int s0 = srcbuf[j];
        uint4 u0 = *(const uint4*)(h1f8 + (size_t)s0 * 256 + l16 * 16);
        accf8(u0.x, a + 0); accf8(u0.y, a + 4); accf8(u0.z, a + 8); accf8(u0.w, a + 12);
    }
    #pragma unroll
    for (int k = 0; k < 16; ++k) a[k] += __shfl_down(a[k], 32);
    #pragma unroll
    for (int k = 0; k < 16; ++k) a[k] += __shfl_down(a[k], 16);
    if (grp == 0) {
        float ri = rinv[node];
        uint4 o0, o1;
        o0.x = (uint32)f2b(a[0] * ri)  | ((uint32)f2b(a[1] * ri) << 16);
        o0.y = (uint32)f2b(a[2] * ri)  | ((uint32)f2b(a[3] * ri) << 16);
        o0.z = (uint32)f2b(a[4] * ri)  | ((uint32)f2b(a[5] * ri) << 16);
        o0.w = (uint32)f2b(a[6] * ri)  | ((uint32)f2b(a[7] * ri) << 16);
        o1.x = (uint32)f2b(a[8] * ri)  | ((uint32)f2b(a[9] * ri) << 16);
        o1.y = (uint32)f2b(a[10] * ri) | ((uint32)f2b(a[11] * ri) << 16);
        o1.z = (uint32)f2b(a[12] * ri) | ((uint32)f2b(a[13] * ri) << 16);
        o1.w = (uint32)f2b(a[14] * ri) | ((uint32)f2b(a[15] * ri) << 16);
        *(uint4*)(h1b + (size_t)node * 512 + 256 + l16 * 16) = o0;
        *(uint4*)(h1b + (size_t)node * 512 + 256 + l16 * 16 + 8) = o1;
    }
}

// ---------------- bf16 MFMA GEMM (128x128 tile, BK=64, XCD-swizzled dispatch) ----------------
template<int KTOT, int OUTSTR, bool POOL, bool FP8OUT, int COLS>
__global__ __launch_bounds__(256) void mfma_gemm(
    const ushort_t* __restrict__ A, const ushort_t* __restrict__ Bt,
    const float* __restrict__ bias,
    ushort_t* __restrict__ outb, uchar_t* __restrict__ outf8,
    float* __restrict__ psum, const int* __restrict__ batch)
{
    __shared__ ushort_t As[8192];       // 128 x 64 k, 16 KB
    __shared__ ushort_t Bs[8192];       // 128 x 64 k, 16 KB
    __shared__ float pool2[8 * 128];    // POOL reduction scratch (4 KB)

    const int id = blockIdx.x;
    const int xcd = id & 7;
    const int s_ = id >> 3;
    const int col = s_ & (COLS - 1);
    const int rloc = s_ / COLS;
    const int rowblk = xcd * RPX + rloc;
    if (rowblk >= RB) return;

    const int tid = threadIdx.x;
    const int lane = tid & 63;
    const int wave = tid >> 6;
    const int quad = lane >> 4;
    const int l16 = lane & 15;
    const int m0w = (wave & 1) * 64;
    const int n0w = (wave >> 1) * 64;
    const int row0 = rowblk * 128;
    const int col0 = col * 128;
    const int Mm1 = N_NODES - 1;

    int st_r[4], st_q[4];
    #pragma unroll
    for (int c = 0; c < 4; ++c) {
        int slot = c * 256 + tid;
        int r = slot >> 3;
        st_r[c] = r;
        st_q[c] = ((slot & 7) ^ (r & 7)) * 8;
    }

    floatx4 acc[4][4] = {};

    for (int kt = 0; kt < KTOT / 64; ++kt) {
        const int kb = kt * 64;
        #pragma unroll
        for (int c = 0; c < 4; ++c) {
            async16(A + (size_t)min(row0 + st_r[c], Mm1) * KTOT + kb + st_q[c],
                    &As[(c * 256 + wave * 64) * 8]);
        }
        #pragma unroll
        for (int c = 0; c < 4; ++c) {
            async16(Bt + (size_t)(col0 + st_r[c]) * KTOT + kb + st_q[c],
                    &Bs[(c * 256 + wave * 64) * 8]);
        }
        __syncthreads();
        #pragma unroll
        for (int kk = 0; kk < 2; ++kk) {
            short8 a[4], b[4];
            #pragma unroll
            for (int t = 0; t < 4; ++t) {
                int r = m0w + t * 16 + l16;
                a[t] = *(const short8*)&As[r * 64 + (((kk * 4 + quad) ^ (r & 7)) * 8)];
            }
            #pragma unroll
            for (int t = 0; t < 4; ++t) {
                int r = n0w + t * 16 + l16;
                b[t] = *(const short8*)&Bs[r * 64 + (((kk * 4 + quad) ^ (r & 7)) * 8)];
            }
            #pragma unroll
            for (int i = 0; i < 4; ++i)
                #pragma unroll
                for (int j = 0; j < 4; ++j)
                    acc[i][j] = __builtin_amdgcn_mfma_f32_16x16x32_bf16(a[i], b[j], acc[i][j], 0, 0, 0);
        }
        __syncthreads();
    }

    float bias4[4];
    #pragma unroll
    for (int j = 0; j < 4; ++j) bias4[j] = bias[col0 + n0w + j * 16 + l16];

    if (!POOL) {
        #pragma unroll
        for (int i = 0; i < 4; ++i) {
            #pragma unroll
            for (int r = 0; r < 4; ++r) {
                int m = row0 + m0w + i * 16 + quad * 4 + r;
                if (m < N_NODES) {
                    #pragma unroll
                    for (int j = 0; j < 4; ++j) {
                        float v = fmaxf(acc[i][j][r] + bias4[j], 0.f);
                        int c = col0 + n0w + j * 16 + l16;
                        outb[(size_t)m * OUTSTR + c] = f2b(v);
                        if (FP8OUT) outf8[(size_t)m * (OUTSTR / 2) + c] = f2f8(v);
                    }
                }
            }
        }
    } else {
        int gmin = batch[row0];
        int gmax = batch[min(row0 + 127, N_NODES - 1)];
        int span = gmax - gmin + 1;
        if (span == 1) {
            float s[4] = {0.f, 0.f, 0.f, 0.f};
            #pragma unroll
            for (int i = 0; i < 4; ++i) {
                #pragma unroll
                for (int r = 0; r < 4; ++r) {
                    int m = row0 + m0w + i * 16 + quad * 4 + r;
                    if (m < N_NODES) {
                        #pragma unroll
                        for (int j = 0; j < 4; ++j)
                            s[j] += fmaxf(acc[i][j][r] + bias4[j], 0.f);
                    }
                }
            }
            int slot = (wave & 1) * 4 + quad;
            #pragma unroll
            for (int j = 0; j < 4; ++j)
                pool2[slot * 128 + n0w + j * 16 + l16] = s[j];
            __syncthreads();
            if (tid < 128) {
                float v = 0.f;
                #pragma unroll
                for (int k = 0; k < 8; ++k) v += pool2[k * 128 + tid];
                atomicAdd(psum + (size_t)gmin * HID + col0 + tid, v);
            }
        } else if (span <= 8) {
            for (int i = tid; i < span * 128; i += 256) pool2[i] = 0.f;
            __syncthreads();
            float s[4] = {0.f, 0.f, 0.f, 0.f};
            int cg = -1;
            #pragma unroll
            for (int i = 0; i < 4; ++i) {
                #pragma unroll
                for (int r = 0; r < 4; ++r) {
                    int m = row0 + m0w + i * 16 + quad * 4 + r;
                    if (m < N_NODES) {
                        int g = batch[m] - gmin;
                        if (g != cg) {
                            if (cg >= 0) {
                                #pragma unroll
                                for (int j = 0; j < 4; ++j)
                                    atomicAdd(&pool2[cg * 128 + n0w + j * 16 + l16], s[j]);
                            }
                            cg = g;
                            s[0] = s[1] = s[2] = s[3] = 0.f;
                        }
                        #pragma unroll
                        for (int j = 0; j < 4; ++j)
                            s[j] += fmaxf(acc[i][j][r] + bias4[j], 0.f);
                    }
                }
            }
            if (cg >= 0) {
                #pragma unroll
                for (int j = 0; j < 4; ++j)
                    atomicAdd(&pool2[cg * 128 + n0w + j * 16 + l16], s[j]);
            }
            __syncthreads();
            for (int i = tid; i < span * 128; i += 256) {
                float v = pool2[i];
                if (v != 0.f)
                    atomicAdd(psum + (size_t)(gmin + (i >> 7)) * HID + col0 + (i & 127), v);
            }
        } else {
            #pragma unroll
            for (int i = 0; i < 4; ++i) {
                #pragma unroll
                for (int r = 0; r < 4; ++r) {
                    int m = row0 + m0w + i * 16 + quad * 4 + r;
                    if (m < N_NODES) {
                        int g = batch[m];
                        #pragma unroll
                        for (int j = 0; j < 4; ++j) {
                            float v = fmaxf(acc[i][j][r] + bias4[j], 0.f);
                            atomicAdd(psum + (size_t)g * HID + col0 + n0w + j * 16 + l16, v);
                        }
                    }
                }
            }
        }
    }
}

// ---------------- head (3-kernel split for parallelism) ----------------
__global__ __launch_bounds__(64) void head_hc_kernel(
    const float* __restrict__ psum, const float* __restrict__ ncnt,
    const float* __restrict__ Wh, const float* __restrict__ bh,
    const float* __restrict__ Wc, const float* __restrict__ bc,
    float* __restrict__ out)
{
    __shared__ float p[HID];
    const int tile = blockIdx.x, g = blockIdx.y, t = threadIdx.x;
    float inv = 1.0f / fmaxf(ncnt[g], 1.0f);
    #pragma unroll
    for (int i = 0; i < 8; ++i)
        p[i * 64 + t] = psum[(size_t)g * HID + i * 64 + t] * inv;
    __syncthreads();
    int col = tile * 64 + t;
    float h = bh[col], c = bc[col];
    #pragma unroll 8
    for (int k = 0; k < HID; ++k) {
        float pk = p[k];
        h += pk * Wh[(size_t)k * HID + col];
        c += pk * Wc[(size_t)k * HID + col];
    }
    out[(size_t)N_GRAPHS * VOCAB + (size_t)g * HID + col] = h;       // hidden
    out[(size_t)2 * N_GRAPHS * VOCAB + (size_t)g * HID + col] = c;   // cell
}

__global__ __launch_bounds__(64) void head_logits_kernel(
    const float* __restrict__ hidden, const float* __restrict__ Wout,
    const float* __restrict__ bout, float* __restrict__ lgt)
{
    __shared__ float hrow[HID];
    const int tile = blockIdx.x, g = blockIdx.y, t = threadIdx.x;
    #pragma unroll
    for (int i = 0; i < 8; ++i)
        hrow[i * 64 + t] = hidden[(size_t)g * HID + i * 64 + t];
    __syncthreads();
    int col = tile * 64 + t;
    float l = bout[col];
    #pragma unroll 8
    for (int k = 0; k < HID; ++k)
        l += hrow[k] * Wout[(size_t)k * VOCAB + col];
    lgt[(size_t)g * VOCAB + col] = l;
}

__global__ __launch_bounds__(512) void head_lsm_kernel(
    const float* __restrict__ lgt, float* __restrict__ out)
{
    __shared__ float redm[8];
    __shared__ float reds[8];
    __shared__ float bm, bs;
    const int g = blockIdx.x, j = threadIdx.x;
    float l = lgt[(size_t)g * VOCAB + j];
    const int lane = j & 63, wave = j >> 6;
    float m = l;
    #pragma unroll
    for (int o = 32; o > 0; o >>= 1) m = fmaxf(m, __shfl_down(m, o));
    if (lane == 0) redm[wave] = m;
    __syncthreads();
    if (j == 0) {
        float mm = redm[0];
        for (int w = 1; w < 8; ++w) mm = fmaxf(mm, redm[w]);
        bm = mm;
    }
    __syncthreads();
    m = bm;
    float e = __expf(l - m);
    float s = e;
    #pragma unroll
    for (int o = 32; o > 0; o >>= 1) s += __shfl_down(s, o);
    if (lane == 0) reds[wave] = s;
    __syncthreads();
    if (j == 0) {
        float ss = 0.f;
        for (int w = 0; w < 8; ++w) ss += reds[w];
        bs = ss;
    }
    __syncthreads();
    out[(size_t)g * VOCAB + j] = l - m - logf(bs);                  // logits
}

// ---------------- launch ----------------
extern "C" void kernel_launch(void* const* d_in, const int* in_sizes, int n_in,
                              void* d_out, int out_size, void* d_ws, size_t ws_size,
                              hipStream_t stream) {
    const float* x      = (const float*)d_in[1];
    const int*   edge   = (const int*)d_in[2];
    const int*   batch  = (const int*)d_in[3];
    const float* Wroot1 = (const float*)d_in[4];
    const float* Wrel1  = (const float*)d_in[5];
    const float* b1     = (const float*)d_in[6];
    const float* Wroot2 = (const float*)d_in[7];
    const float* Wrel2  = (const float*)d_in[8];
    const float* b2     = (const float*)d_in[9];
    const float* Wh     = (const float*)d_in[10];
    const float* bh     = (const float*)d_in[11];
    const float* Wc     = (const float*)d_in[12];
    const float* bc     = (const float*)d_in[13];
    const float* Wout   = (const float*)d_in[14];
    const float* bout   = (const float*)d_in[15];
    float* out = (float*)d_out;

    // workspace layout
    int*      deg_i   = (int*)d_ws;                        // 50000 (zeroed)
    int*      cursor  = deg_i + N_NODES;                   // 50000 (init by scan_final)
    float*    ncnt    = (float*)(cursor + N_NODES);        // 64
    float*    psum    = ncnt + N_GRAPHS;                   // 32768 (zeroed)
    int*      offsets = (int*)(psum + N_GRAPHS * HID);     // 50001
    int*      srcbuf  = offsets + (N_NODES + 1);           // 800000
    int*      bsum    = srcbuf + N_EDGES;                  // 256
    int*      bbase   = bsum + 256;                        // 256
    float*    rinv    = (float*)(bbase + 256);             // 50000 (+3 pad)
    ushort_t* xb      = (ushort_t*)(rinv + N_NODES + 3);   // 50000*256 bf16
    ushort_t* h1b     = xb + (size_t)N_NODES * 256;        // 50000*512 bf16
    ushort_t* w1t     = h1b + (size_t)N_NODES * 512;       // 256*256
    ushort_t* w2t     = w1t + 256 * 256;                   // 512*512
    uchar_t*  h1f8    = (uchar_t*)(w2t + 512 * 512);       // 50000*256 fp8
    float*    lgt     = (float*)(h1f8 + (size_t)N_NODES * 256); // 64*512 raw logits
    uchar_t*  xf8     = (uchar_t*)(lgt + N_GRAPHS * VOCAB);     // 50000*128 fp8

    const size_t zero_bytes = (size_t)(2 * N_NODES + N_GRAPHS + N_GRAPHS * HID) * 4;
    hipMemsetAsync(d_ws, 0, zero_bytes, stream);

    deg_kernel<<<8 * NBF, 256, 0, stream>>>(edge, deg_i);
    scan_part_kernel<<<SCAN_NB, SCAN_B, 0, stream>>>(deg_i, bsum);
    scan_base_kernel<<<1, SCAN_B, 0, stream>>>(bsum, bbase, batch, ncnt);
    scan_final_kernel<<<SCAN_NB, SCAN_B, 0, stream>>>(deg_i, bbase, offsets, cursor, rinv);
    fill_kernel<<<8 * NBF, 256, 0, stream>>>(edge, cursor, srcbuf);

    conv_all_kernel<<<(N_NODES * 32 + 256 * 256 + 512 * 512) / 256, 256, 0, stream>>>(
        x, Wroot1, Wrel1, Wroot2, Wrel2, xb, xf8, w1t, w2t);

    gather1_kernel<<<(N_NODES + 3) / 4, 256, 0, stream>>>(offsets, srcbuf, rinv, xf8, xb);

    {   // layer 1: A=xb [50000 x 256] bf16 -> h1b cols 0..255 (+ fp8 copy); COLS=2
        mfma_gemm<256, 512, false, true, 2><<<8 * RPX * 2, 256, 0, stream>>>(
            xb, w1t, b1, h1b, h1f8, nullptr, nullptr);
    }

    gather2_kernel<<<(N_NODES + 3) / 4, 256, 0, stream>>>(offsets, srcbuf, rinv, h1f8, h1b);

    {   // layer 2: A=h1b [50000 x 512] bf16 -> pooled psum; COLS=4
        mfma_gemm<512, 512, true, false, 4><<<8 * RPX * 4, 256, 0, stream>>>(
            h1b, w2t, b2, nullptr, nullptr, psum, batch);
    }

    head_hc_kernel<<<dim3(8, 64), 64, 0, stream>>>(psum, ncnt, Wh, bh, Wc, bc, out);
    head_logits_kernel<<<dim3(8, 64), 64, 0, stream>>>(
        out + (size_t)N_GRAPHS * VOCAB, Wout, bout, lgt);
    head_lsm_kernel<<<N_GRAPHS, 512, 0, stream>>>(lgt, out);
}

// Round 15
// 391.495 us; speedup vs baseline: 1.1420x; 1.0333x over previous
//
#include <hip/hip_runtime.h>
#include <hip/hip_bf16.h>

#define N_NODES 50000
#define N_EDGES 800000
#define N_GRAPHS 64
#define FEAT 128
#define EMB 256
#define HID 512
#define VOCAB 512

#define SCAN_B 256
#define SCAN_NB ((N_NODES + SCAN_B - 1) / SCAN_B)   // 196
#define RB ((N_NODES + 127) / 128)                  // 391 row-blocks
#define RPX ((RB + 7) / 8)                          // 49 row-blocks per XCD
#define DRANGE ((N_NODES + 7) / 8)                  // 6250 dst per partition
#define EPT 8                                       // edges/thread in deg/fill
#define EPB (256 * EPT)                             // 2048 edges/block
#define NBF ((N_EDGES + EPB - 1) / EPB)             // 391 slices
#define DEG_BLOCKS (8 * NBF)                        // 3128
#define CONV_ELEMS (N_NODES * 32 + 256 * 256 + 512 * 512)  // 1,927,680
#define CONV_BLOCKS (CONV_ELEMS / 256)              // 7530

typedef __attribute__((ext_vector_type(8))) short short8;
typedef __attribute__((ext_vector_type(4))) float floatx4;
typedef __attribute__((ext_vector_type(2))) float floatx2;
typedef unsigned short ushort_t;
typedef unsigned int uint32;
typedef unsigned char uchar_t;

__device__ __forceinline__ ushort_t f2b(float f) {
    uint32 u = __builtin_bit_cast(uint32, f);
    u += 0x7fffu + ((u >> 16) & 1u);
    return (ushort_t)(u >> 16);
}
__device__ __forceinline__ float b2f(ushort_t h) {
    uint32 u = ((uint32)h) << 16;
    return __builtin_bit_cast(float, u);
}
// u holds 4 fp8 e4m3; accumulate into a[0..3]
__device__ __forceinline__ void accf8(uint32 u, float* a) {
    floatx2 lo = __builtin_amdgcn_cvt_pk_f32_fp8(u, false);
    floatx2 hi = __builtin_amdgcn_cvt_pk_f32_fp8(u, true);
    a[0] += lo[0]; a[1] += lo[1]; a[2] += hi[0]; a[3] += hi[1];
}
__device__ __forceinline__ uchar_t f2f8(float v) {
    return (uchar_t)(__builtin_amdgcn_cvt_pk_fp8_f32(v, v, 0, false) & 0xff);
}
__device__ __forceinline__ void async16(const void* g, void* l) {
    __builtin_amdgcn_global_load_lds(
        (const __attribute__((address_space(1))) void*)g,
        (__attribute__((address_space(3))) void*)l, 16, 0, 0);
}

// ---------------- prep: deg histogram (dst-partitioned) + all converts, one launch ----------------
__global__ void prep_kernel(const int* __restrict__ edge, int* __restrict__ deg,
                            const float* __restrict__ x,
                            const float* __restrict__ W01, const float* __restrict__ W11,
                            const float* __restrict__ W02, const float* __restrict__ W12,
                            ushort_t* __restrict__ xb, uchar_t* __restrict__ xf8,
                            ushort_t* __restrict__ w1t, ushort_t* __restrict__ w2t) {
    if (blockIdx.x < DEG_BLOCKS) {
        int grp = blockIdx.x & 7;
        int slice = blockIdx.x >> 3;
        int dlo = grp * DRANGE;
        int dhi = min(dlo + DRANGE, N_NODES);
        int base = slice * EPB + threadIdx.x;
        #pragma unroll
        for (int i = 0; i < EPT; ++i) {
            int e = base + i * 256;
            if (e < N_EDGES) {
                int dst = edge[N_EDGES + e];
                if (dst >= dlo && dst < dhi) atomicAdd(deg + dst, 1);
            }
        }
    } else {
        int tid = (blockIdx.x - DEG_BLOCKS) * 256 + threadIdx.x;
        if (tid < N_NODES * 32) {
            int row = tid >> 5, c = (tid & 31) * 4;
            float4 v = *(const float4*)(x + (size_t)row * FEAT + c);
            ushort4 o;
            o.x = f2b(v.x); o.y = f2b(v.y); o.z = f2b(v.z); o.w = f2b(v.w);
            *(ushort4*)(xb + (size_t)row * (2 * FEAT) + c) = o;
            uint32 p = __builtin_amdgcn_cvt_pk_fp8_f32(v.x, v.y, 0, false);
            p = __builtin_amdgcn_cvt_pk_fp8_f32(v.z, v.w, p, true);
            *(uint32*)(xf8 + (size_t)row * FEAT + c) = p;
        } else if (tid < N_NODES * 32 + 256 * 256) {
            int t1 = tid - N_NODES * 32;
            int n = t1 >> 8, k = t1 & 255;
            float v = (k < 128) ? W01[(size_t)k * 256 + n] : W11[(size_t)(k - 128) * 256 + n];
            w1t[t1] = f2b(v);
        } else {
            int t2 = tid - N_NODES * 32 - 256 * 256;
            int n = t2 >> 9, k = t2 & 511;
            float v = (k < 256) ? W02[(size_t)k * 512 + n] : W12[(size_t)(k - 256) * 512 + n];
            w2t[t2] = f2b(v);
        }
    }
}

// ---- 2-phase scan: per-block sums, then final (base recomputed per-block) ----
__global__ __launch_bounds__(SCAN_B) void scan_part_kernel(const int* __restrict__ deg,
                                                           int* __restrict__ blocksum) {
    __shared__ int s[SCAN_B];
    int i = blockIdx.x * SCAN_B + threadIdx.x;
    int t = threadIdx.x;
    s[t] = (i < N_NODES) ? deg[i] : 0;
    __syncthreads();
    #pragma unroll
    for (int off = SCAN_B / 2; off > 0; off >>= 1) {
        if (t < off) s[t] += s[t + off];
        __syncthreads();
    }
    if (t == 0) blocksum[blockIdx.x] = s[0];
}

// final: each block scans the 196 block-sums in LDS for its own base (saves a
// kernel + gap vs separate scan_base), writes offsets/cursor/rinv; block 0 also
// computes ncnt via binary search on the sorted batch array.
__global__ __launch_bounds__(SCAN_B) void scan_final_kernel(const int* __restrict__ deg,
                                                            const int* __restrict__ blocksum,
                                                            int* __restrict__ offsets,
                                                            int* __restrict__ cursor,
                                                            float* __restrict__ rinv,
                                                            const int* __restrict__ batch,
                                                            float* __restrict__ ncnt) {
    __shared__ int bs_[SCAN_B];
    __shared__ int s[SCAN_B];
    int t = threadIdx.x;
    int bv = (t < SCAN_NB) ? blocksum[t] : 0;
    bs_[t] = bv;
    __syncthreads();
    #pragma unroll
    for (int off = 1; off < SCAN_B; off <<= 1) {
        int u = (t >= off) ? bs_[t - off] : 0;
        __syncthreads();
        bs_[t] += u;
        __syncthreads();
    }
    int base = (blockIdx.x == 0) ? 0 : bs_[blockIdx.x - 1];

    int i = blockIdx.x * SCAN_B + t;
    int v = (i < N_NODES) ? deg[i] : 0;
    s[t] = v;
    __syncthreads();
    #pragma unroll
    for (int off = 1; off < SCAN_B; off <<= 1) {
        int u = (t >= off) ? s[t - off] : 0;
        __syncthreads();
        s[t] += u;
        __syncthreads();
    }
    int excl = s[t] - v + base;
    if (i < N_NODES) {
        offsets[i] = excl;
        cursor[i] = excl;
        rinv[i] = 1.0f / (float)max(v, 1);
    }
    if (i == N_NODES - 1) offsets[N_NODES] = excl + v;

    if (blockIdx.x == 0 && t < N_GRAPHS) {
        int g = t;
        int lo = 0, hi = N_NODES;
        while (lo < hi) { int mid = (lo + hi) >> 1; if (batch[mid] < g) lo = mid + 1; else hi = mid; }
        int lo2 = lo, hi2 = N_NODES;
        while (lo2 < hi2) { int mid = (lo2 + hi2) >> 1; if (batch[mid] < g + 1) lo2 = mid + 1; else hi2 = mid; }
        ncnt[g] = (float)(lo2 - lo);
    }
}

__global__ void fill_kernel(const int* __restrict__ edge,
                            int* __restrict__ cursor, int* __restrict__ srcbuf) {
    int grp = blockIdx.x & 7;
    int slice = blockIdx.x >> 3;
    int dlo = grp * DRANGE;
    int dhi = min(dlo + DRANGE, N_NODES);
    int base = slice * EPB + threadIdx.x;
    #pragma unroll
    for (int i = 0; i < EPT; ++i) {
        int e = base + i * 256;
        if (e < N_EDGES) {
            int dst = edge[N_EDGES + e];
            if (dst >= dlo && dst < dhi) {
                int pos = atomicAdd(cursor + dst, 1);
                srcbuf[pos] = edge[e];
            }
        }
    }
}

// ---------------- CSR gathers ----------------
// gather1: fp8 source (128 B/row); 8 lane-groups of 8 -> 8 edges per instruction
__global__ __launch_bounds__(256) void gather1_kernel(
    const int* __restrict__ offsets, const int* __restrict__ srcbuf,
    const float* __restrict__ rinv, const uchar_t* __restrict__ xf8,
    ushort_t* __restrict__ xb)
{
    int node = blockIdx.x * 4 + (threadIdx.x >> 6);
    if (node >= N_NODES) return;
    int lane = threadIdx.x & 63;
    int grp = lane >> 3;
    int l8 = lane & 7;
    int beg = offsets[node], end = offsets[node + 1];

    float a[16];
    #pragma unroll
    for (int k = 0; k < 16; ++k) a[k] = 0.f;

    int j = beg + grp;
    for (; j + 8 < end; j += 16) {
        int s0 = srcbuf[j];
        int s1 = srcbuf[j + 8];
        uint4 u0 = *(const uint4*)(xf8 + (size_t)s0 * FEAT + l8 * 16);
        uint4 u1 = *(const uint4*)(xf8 + (size_t)s1 * FEAT + l8 * 16);
        accf8(u0.x, a + 0); accf8(u0.y, a + 4); accf8(u0.z, a + 8); accf8(u0.w, a + 12);
        accf8(u1.x, a + 0); accf8(u1.y, a + 4); accf8(u1.z, a + 8); accf8(u1.w, a + 12);
    }
    for (; j < end; j += 8) {
        int s0 = srcbuf[j];
        uint4 u0 = *(const uint4*)(xf8 + (size_t)s0 * FEAT + l8 * 16);
        accf8(u0.x, a + 0); accf8(u0.y, a + 4); accf8(u0.z, a + 8); accf8(u0.w, a + 12);
    }
    #pragma unroll
    for (int k = 0; k < 16; ++k) a[k] += __shfl_down(a[k], 32);
    #pragma unroll
    for (int k = 0; k < 16; ++k) a[k] += __shfl_down(a[k], 16);
    #pragma unroll
    for (int k = 0; k < 16; ++k) a[k] += __shfl_down(a[k], 8);
    if (grp == 0) {
        float ri = rinv[node];
        uint4 o0, o1;
        o0.x = (uint32)f2b(a[0] * ri)  | ((uint32)f2b(a[1] * ri) << 16);
        o0.y = (uint32)f2b(a[2] * ri)  | ((uint32)f2b(a[3] * ri) << 16);
        o0.z = (uint32)f2b(a[4] * ri)  | ((uint32)f2b(a[5] * ri) << 16);
        o0.w = (uint32)f2b(a[6] * ri)  | ((uint32)f2b(a[7] * ri) << 16);
        o1.x = (uint32)f2b(a[8] * ri)  | ((uint32)f2b(a[9] * ri) << 16);
        o1.y = (uint32)f2b(a[10] * ri) | ((uint32)f2b(a[11] * ri) << 16);
        o1.z = (uint32)f2b(a[12] * ri) | ((uint32)f2b(a[13] * ri) << 16);
        o1.w = (uint32)f2b(a[14] * ri) | ((uint32)f2b(a[15] * ri) << 16);
        *(uint4*)(xb + (size_t)node * 256 + 128 + l8 * 16) = o0;
        *(uint4*)(xb + (size_t)node * 256 + 128 + l8 * 16 + 8) = o1;
    }
}

// gather2: fp8 source (256 B/row); 4 lane-groups of 16, lane covers 16 cols
__global__ __launch_bounds__(256) void gather2_kernel(
    const int* __restrict__ offsets, const int* __restrict__ srcbuf,
    const float* __restrict__ rinv, const uchar_t* __restrict__ h1f8,
    ushort_t* __restrict__ h1b)
{
    int node = blockIdx.x * 4 + (threadIdx.x >> 6);
    if (node >= N_NODES) return;
    int lane = threadIdx.x & 63;
    int grp = lane >> 4;
    int l16 = lane & 15;
    int beg = offsets[node], end = offsets[node + 1];

    float a[16];
    #pragma unroll
    for (int k = 0; k < 16; ++k) a[k] = 0.f;

    int j = beg + grp;
    for (; j + 4 < end; j += 8) {
        int s0 = srcbuf[j];
        int s1 = srcbuf[j + 4];
        uint4 u0 = *(const uint4*)(h1f8 + (size_t)s0 * 256 + l16 * 16);
        uint4 u1 = *(const uint4*)(h1f8 + (size_t)s1 * 256 + l16 * 16);
        accf8(u0.x, a + 0); accf8(u0.y, a + 4); accf8(u0.z, a + 8); accf8(u0.w, a + 12);
        accf8(u1.x, a + 0); accf8(u1.y, a + 4); accf8(u1.z, a + 8); accf8(u1.w, a + 12);
    }
    for (; j < end; j += 4) {
        int s0 = srcbuf[j];
        uint4 u0 = *(const uint4*)(h1f8 + (size_t)s0 * 256 + l16 * 16);
        accf8(u0.x, a + 0); accf8(u0.y, a + 4); accf8(u0.z, a + 8); accf8(u0.w, a + 12);
    }
    #pragma unroll
    for (int k = 0; k < 16; ++k) a[k] += __shfl_down(a[k], 32);
    #pragma unroll
    for (int k = 0; k < 16; ++k) a[k] += __shfl_down(a[k], 16);
    if (grp == 0) {
        float ri = rinv[node];
        uint4 o0, o1;
        o0.x = (uint32)f2b(a[0] * ri)  | ((uint32)f2b(a[1] * ri) << 16);
        o0.y = (uint32)f2b(a[2] * ri)  | ((uint32)f2b(a[3] * ri) << 16);
        o0.z = (uint32)f2b(a[4] * ri)  | ((uint32)f2b(a[5] * ri) << 16);
        o0.w = (uint32)f2b(a[6] * ri)  | ((uint32)f2b(a[7] * ri) << 16);
        o1.x = (uint32)f2b(a[8] * ri)  | ((uint32)f2b(a[9] * ri) << 16);
        o1.y = (uint32)f2b(a[10] * ri) | ((uint32)f2b(a[11] * ri) << 16);
        o1.z = (uint32)f2b(a[12] * ri) | ((uint32)f2b(a[13] * ri) << 16);
        o1.w = (uint32)f2b(a[14] * ri) | ((uint32)f2b(a[15] * ri) << 16);
        *(uint4*)(h1b + (size_t)node * 512 + 256 + l16 * 16) = o0;
        *(uint4*)(h1b + (size_t)node * 512 + 256 + l16 * 16 + 8) = o1;
    }
}

// ---------------- bf16 MFMA GEMM (128x128 tile, BK=64, XCD-swizzled dispatch) ----------------
template<int KTOT, int OUTSTR, bool POOL, bool FP8OUT, int COLS>
__global__ __launch_bounds__(256) void mfma_gemm(
    const ushort_t* __restrict__ A, const ushort_t* __restrict__ Bt,
    const float* __restrict__ bias,
    ushort_t* __restrict__ outb, uchar_t* __restrict__ outf8,
    float* __restrict__ psum, const int* __restrict__ batch)
{
    __shared__ ushort_t As[8192];
    __shared__ ushort_t Bs[8192];
    __shared__ float pool2[8 * 128];

    const int id = blockIdx.x;
    const int xcd = id & 7;
    const int s_ = id >> 3;
    const int col = s_ & (COLS - 1);
    const int rloc = s_ / COLS;
    const int rowblk = xcd * RPX + rloc;
    if (rowblk >= RB) return;

    const int tid = threadIdx.x;
    const int lane = tid & 63;
    const int wave = tid >> 6;
    const int quad = lane >> 4;
    const int l16 = lane & 15;
    const int m0w = (wave & 1) * 64;
    const int n0w = (wave >> 1) * 64;
    const int row0 = rowblk * 128;
    const int col0 = col * 128;
    const int Mm1 = N_NODES - 1;

    int st_r[4], st_q[4];
    #pragma unroll
    for (int c = 0; c < 4; ++c) {
        int slot = c * 256 + tid;
        int r = slot >> 3;
        st_r[c] = r;
        st_q[c] = ((slot & 7) ^ (r & 7)) * 8;
    }

    floatx4 acc[4][4] = {};

    for (int kt = 0; kt < KTOT / 64; ++kt) {
        const int kb = kt * 64;
        #pragma unroll
        for (int c = 0; c < 4; ++c) {
            async16(A + (size_t)min(row0 + st_r[c], Mm1) * KTOT + kb + st_q[c],
                    &As[(c * 256 + wave * 64) * 8]);
        }
        #pragma unroll
        for (int c = 0; c < 4; ++c) {
            async16(Bt + (size_t)(col0 + st_r[c]) * KTOT + kb + st_q[c],
                    &Bs[(c * 256 + wave * 64) * 8]);
        }
        __syncthreads();
        #pragma unroll
        for (int kk = 0; kk < 2; ++kk) {
            short8 a[4], b[4];
            #pragma unroll
            for (int t = 0; t < 4; ++t) {
                int r = m0w + t * 16 + l16;
                a[t] = *(const short8*)&As[r * 64 + (((kk * 4 + quad) ^ (r & 7)) * 8)];
            }
            #pragma unroll
            for (int t = 0; t < 4; ++t) {
                int r = n0w + t * 16 + l16;
                b[t] = *(const short8*)&Bs[r * 64 + (((kk * 4 + quad) ^ (r & 7)) * 8)];
            }
            #pragma unroll
            for (int i = 0; i < 4; ++i)
                #pragma unroll
                for (int j = 0; j < 4; ++j)
                    acc[i][j] = __builtin_amdgcn_mfma_f32_16x16x32_bf16(a[i], b[j], acc[i][j], 0, 0, 0);
        }
        __syncthreads();
    }

    float bias4[4];
    #pragma unroll
    for (int j = 0; j < 4; ++j) bias4[j] = bias[col0 + n0w + j * 16 + l16];

    if (!POOL) {
        #pragma unroll
        for (int i = 0; i < 4; ++i) {
            #pragma unroll
            for (int r = 0; r < 4; ++r) {
                int m = row0 + m0w + i * 16 + quad * 4 + r;
                if (m < N_NODES) {
                    #pragma unroll
                    for (int j = 0; j < 4; ++j) {
                        float v = fmaxf(acc[i][j][r] + bias4[j], 0.f);
                        int c = col0 + n0w + j * 16 + l16;
                        outb[(size_t)m * OUTSTR + c] = f2b(v);
                        if (FP8OUT) outf8[(size_t)m * (OUTSTR / 2) + c] = f2f8(v);
                    }
                }
            }
        }
    } else {
        int gmin = batch[row0];
        int gmax = batch[min(row0 + 127, N_NODES - 1)];
        int span = gmax - gmin + 1;
        if (span == 1) {
            float s[4] = {0.f, 0.f, 0.f, 0.f};
            #pragma unroll
            for (int i = 0; i < 4; ++i) {
                #pragma unroll
                for (int r = 0; r < 4; ++r) {
                    int m = row0 + m0w + i * 16 + quad * 4 + r;
                    if (m < N_NODES) {
                        #pragma unroll
                        for (int j = 0; j < 4; ++j)
                            s[j] += fmaxf(acc[i][j][r] + bias4[j], 0.f);
                    }
                }
            }
            int slot = (wave & 1) * 4 + quad;
            #pragma unroll
            for (int j = 0; j < 4; ++j)
                pool2[slot * 128 + n0w + j * 16 + l16] = s[j];
            __syncthreads();
            if (tid < 128) {
                float v = 0.f;
                #pragma unroll
                for (int k = 0; k < 8; ++k) v += pool2[k * 128 + tid];
                atomicAdd(psum + (size_t)gmin * HID + col0 + tid, v);
            }
        } else if (span <= 8) {
            for (int i = tid; i < span * 128; i += 256) pool2[i] = 0.f;
            __syncthreads();
            float s[4] = {0.f, 0.f, 0.f, 0.f};
            int cg = -1;
            #pragma unroll
            for (int i = 0; i < 4; ++i) {
                #pragma unroll
                for (int r = 0; r < 4; ++r) {
                    int m = row0 + m0w + i * 16 + quad * 4 + r;
                    if (m < N_NODES) {
                        int g = batch[m] - gmin;
                        if (g != cg) {
                            if (cg >= 0) {
                                #pragma unroll
                                for (int j = 0; j < 4; ++j)
                                    atomicAdd(&pool2[cg * 128 + n0w + j * 16 + l16], s[j]);
                            }
                            cg = g;
                            s[0] = s[1] = s[2] = s[3] = 0.f;
                        }
                        #pragma unroll
                        for (int j = 0; j < 4; ++j)
                            s[j] += fmaxf(acc[i][j][r] + bias4[j], 0.f);
                    }
                }
            }
            if (cg >= 0) {
                #pragma unroll
                for (int j = 0; j < 4; ++j)
                    atomicAdd(&pool2[cg * 128 + n0w + j * 16 + l16], s[j]);
            }
            __syncthreads();
            for (int i = tid; i < span * 128; i += 256) {
                float v = pool2[i];
                if (v != 0.f)
                    atomicAdd(psum + (size_t)(gmin + (i >> 7)) * HID + col0 + (i & 127), v);
            }
        } else {
            #pragma unroll
            for (int i = 0; i < 4; ++i) {
                #pragma unroll
                for (int r = 0; r < 4; ++r) {
                    int m = row0 + m0w + i * 16 + quad * 4 + r;
                    if (m < N_NODES) {
                        int g = batch[m];
                        #pragma unroll
                        for (int j = 0; j < 4; ++j) {
                            float v = fmaxf(acc[i][j][r] + bias4[j], 0.f);
                            atomicAdd(psum + (size_t)g * HID + col0 + n0w + j * 16 + l16, v);
                        }
                    }
                }
            }
        }
    }
}

// ---------------- head ----------------
__global__ __launch_bounds__(64) void head_hc_kernel(
    const float* __restrict__ psum, const float* __restrict__ ncnt,
    const float* __restrict__ Wh, const float* __restrict__ bh,
    const float* __restrict__ Wc, const float* __restrict__ bc,
    float* __restrict__ out)
{
    __shared__ float p[HID];
    const int tile = blockIdx.x, g = blockIdx.y, t = threadIdx.x;
    float inv = 1.0f / fmaxf(ncnt[g], 1.0f);
    #pragma unroll
    for (int i = 0; i < 8; ++i)
        p[i * 64 + t] = psum[(size_t)g * HID + i * 64 + t] * inv;
    __syncthreads();
    int col = tile * 64 + t;
    float h = bh[col], c = bc[col];
    #pragma unroll 8
    for (int k = 0; k < HID; ++k) {
        float pk = p[k];
        h += pk * Wh[(size_t)k * HID + col];
        c += pk * Wc[(size_t)k * HID + col];
    }
    out[(size_t)N_GRAPHS * VOCAB + (size_t)g * HID + col] = h;       // hidden
    out[(size_t)2 * N_GRAPHS * VOCAB + (size_t)g * HID + col] = c;   // cell
}

// fused logits + log_softmax: one block per graph, 512 threads
__global__ __launch_bounds__(512) void head_out_kernel(
    const float* __restrict__ hidden, const float* __restrict__ Wout,
    const float* __restrict__ bout, float* __restrict__ out)
{
    __shared__ float hrow[HID];
    __shared__ float redm[8];
    __shared__ float reds[8];
    __shared__ float bm, bs;
    const int g = blockIdx.x, j = threadIdx.x;
    hrow[j] = hidden[(size_t)g * HID + j];
    __syncthreads();
    float l = bout[j];
    #pragma unroll 8
    for (int k = 0; k < HID; ++k)
        l += hrow[k] * Wout[(size_t)k * VOCAB + j];

    const int lane = j & 63, wave = j >> 6;
    float m = l;
    #pragma unroll
    for (int o = 32; o > 0; o >>= 1) m = fmaxf(m, __shfl_down(m, o));
    if (lane == 0) redm[wave] = m;
    __syncthreads();
    if (j == 0) {
        float mm = redm[0];
        for (int w = 1; w < 8; ++w) mm = fmaxf(mm, redm[w]);
        bm = mm;
    }
    __syncthreads();
    m = bm;
    float e = __expf(l - m);
    float s = e;
    #pragma unroll
    for (int o = 32; o > 0; o >>= 1) s += __shfl_down(s, o);
    if (lane == 0) reds[wave] = s;
    __syncthreads();
    if (j == 0) {
        float ss = 0.f;
        for (int w = 0; w < 8; ++w) ss += reds[w];
        bs = ss;
    }
    __syncthreads();
    out[(size_t)g * VOCAB + j] = l - m - logf(bs);                  // logits
}

// ---------------- launch ----------------
extern "C" void kernel_launch(void* const* d_in, const int* in_sizes, int n_in,
                              void* d_out, int out_size, void* d_ws, size_t ws_size,
                              hipStream_t stream) {
    const float* x      = (const float*)d_in[1];
    const int*   edge   = (const int*)d_in[2];
    const int*   batch  = (const int*)d_in[3];
    const float* Wroot1 = (const float*)d_in[4];
    const float* Wrel1  = (const float*)d_in[5];
    const float* b1     = (const float*)d_in[6];
    const float* Wroot2 = (const float*)d_in[7];
    const float* Wrel2  = (const float*)d_in[8];
    const float* b2     = (const float*)d_in[9];
    const float* Wh     = (const float*)d_in[10];
    const float* bh     = (const float*)d_in[11];
    const float* Wc     = (const float*)d_in[12];
    const float* bc     = (const float*)d_in[13];
    const float* Wout   = (const float*)d_in[14];
    const float* bout   = (const float*)d_in[15];
    float* out = (float*)d_out;

    // workspace layout: deg+psum first (single minimal memset)
    int*      deg_i   = (int*)d_ws;                        // 50000 (zeroed)
    float*    psum    = (float*)(deg_i + N_NODES);         // 32768 (zeroed)
    int*      cursor  = (int*)(psum + N_GRAPHS * HID);     // 50000 (init by scan_final)
    float*    ncnt    = (float*)(cursor + N_NODES);        // 64
    int*      offsets = (int*)(ncnt + N_GRAPHS);           // 50001
    int*      srcbuf  = offsets + (N_NODES + 1);           // 800000
    int*      bsum    = srcbuf + N_EDGES;                  // 256
    int*      pad_    = bsum + 256;                        // 256 (keeps alignment)
    float*    rinv    = (float*)(pad_ + 256);              // 50000 (+3 pad)
    ushort_t* xb      = (ushort_t*)(rinv + N_NODES + 3);   // 50000*256 bf16
    ushort_t* h1b     = xb + (size_t)N_NODES * 256;        // 50000*512 bf16
    ushort_t* w1t     = h1b + (size_t)N_NODES * 512;       // 256*256
    ushort_t* w2t     = w1t + 256 * 256;                   // 512*512
    uchar_t*  h1f8    = (uchar_t*)(w2t + 512 * 512);       // 50000*256 fp8
    float*    lgt     = (float*)(h1f8 + (size_t)N_NODES * 256); // unused slot
    uchar_t*  xf8     = (uchar_t*)(lgt + N_GRAPHS * VOCAB);     // 50000*128 fp8
    (void)lgt;

    // zero deg + psum only (contiguous, 331 KB)
    hipMemsetAsync(d_ws, 0, (size_t)(N_NODES + N_GRAPHS * HID) * 4, stream);

    prep_kernel<<<DEG_BLOCKS + CONV_BLOCKS, 256, 0, stream>>>(
        edge, deg_i, x, Wroot1, Wrel1, Wroot2, Wrel2, xb, xf8, w1t, w2t);
    scan_part_kernel<<<SCAN_NB, SCAN_B, 0, stream>>>(deg_i, bsum);
    scan_final_kernel<<<SCAN_NB, SCAN_B, 0, stream>>>(
        deg_i, bsum, offsets, cursor, rinv, batch, ncnt);
    fill_kernel<<<8 * NBF, 256, 0, stream>>>(edge, cursor, srcbuf);

    gather1_kernel<<<(N_NODES + 3) / 4, 256, 0, stream>>>(offsets, srcbuf, rinv, xf8, xb);

    {   // layer 1: A=xb [50000 x 256] bf16 -> h1b cols 0..255 (+ fp8 copy); COLS=2
        mfma_gemm<256, 512, false, true, 2><<<8 * RPX * 2, 256, 0, stream>>>(
            xb, w1t, b1, h1b, h1f8, nullptr, nullptr);
    }

    gather2_kernel<<<(N_NODES + 3) / 4, 256, 0, stream>>>(offsets, srcbuf, rinv, h1f8, h1b);

    {   // layer 2: A=h1b [50000 x 512] bf16 -> pooled psum; COLS=4
        mfma_gemm<512, 512, true, false, 4><<<8 * RPX * 4, 256, 0, stream>>>(
            h1b, w2t, b2, nullptr, nullptr, psum, batch);
    }

    head_hc_kernel<<<dim3(8, 64), 64, 0, stream>>>(psum, ncnt, Wh, bh, Wc, bc, out);
    head_out_kernel<<<N_GRAPHS, 512, 0, stream>>>(
        out + (size_t)N_GRAPHS * VOCAB, Wout, bout, out);
}

// Round 16
// 375.217 us; speedup vs baseline: 1.1915x; 1.0434x over previous
//
#include <hip/hip_runtime.h>
#include <hip/hip_bf16.h>

#define N_NODES 50000
#define N_EDGES 800000
#define N_GRAPHS 64
#define FEAT 128
#define EMB 256
#define HID 512
#define VOCAB 512

#define SCAN_B 256
#define SCAN_NB ((N_NODES + SCAN_B - 1) / SCAN_B)   // 196
#define RB ((N_NODES + 127) / 128)                  // 391 row-blocks
#define RPX ((RB + 7) / 8)                          // 49 row-blocks per XCD
#define DRANGE ((N_NODES + 7) / 8)                  // 6250 dst per partition
#define EPT 8                                       // edges/thread in deg/fill
#define EPB (256 * EPT)                             // 2048 edges/block
#define NBF ((N_EDGES + EPB - 1) / EPB)             // 391 slices
#define DEG_BLOCKS (8 * NBF)                        // 3128
#define CONV_ELEMS (N_NODES * 32 + 256 * 256 + 512 * 512)  // 1,927,680
#define CONV_BLOCKS (CONV_ELEMS / 256)              // 7530

typedef __attribute__((ext_vector_type(8))) short short8;
typedef __attribute__((ext_vector_type(4))) float floatx4;
typedef __attribute__((ext_vector_type(2))) float floatx2;
typedef unsigned short ushort_t;
typedef unsigned int uint32;
typedef unsigned char uchar_t;

__device__ __forceinline__ ushort_t f2b(float f) {
    uint32 u = __builtin_bit_cast(uint32, f);
    u += 0x7fffu + ((u >> 16) & 1u);
    return (ushort_t)(u >> 16);
}
__device__ __forceinline__ float b2f(ushort_t h) {
    uint32 u = ((uint32)h) << 16;
    return __builtin_bit_cast(float, u);
}
// u holds 4 fp8 e4m3; accumulate into a[0..3]
__device__ __forceinline__ void accf8(uint32 u, float* a) {
    floatx2 lo = __builtin_amdgcn_cvt_pk_f32_fp8(u, false);
    floatx2 hi = __builtin_amdgcn_cvt_pk_f32_fp8(u, true);
    a[0] += lo[0]; a[1] += lo[1]; a[2] += hi[0]; a[3] += hi[1];
}
__device__ __forceinline__ uchar_t f2f8(float v) {
    return (uchar_t)(__builtin_amdgcn_cvt_pk_fp8_f32(v, v, 0, false) & 0xff);
}
__device__ __forceinline__ uint32 pk4f8(float a, float b, float c, float d) {
    uint32 w = __builtin_amdgcn_cvt_pk_fp8_f32(a, b, 0, false);
    return __builtin_amdgcn_cvt_pk_fp8_f32(c, d, w, true);
}
__device__ __forceinline__ void async16(const void* g, void* l) {
    __builtin_amdgcn_global_load_lds(
        (const __attribute__((address_space(1))) void*)g,
        (__attribute__((address_space(3))) void*)l, 16, 0, 0);
}

// ---------------- prep: deg histogram (dst-partitioned) + all converts ----------------
__global__ void prep_kernel(const int* __restrict__ edge, int* __restrict__ deg,
                            const float* __restrict__ x,
                            const float* __restrict__ W01, const float* __restrict__ W11,
                            const float* __restrict__ W02, const float* __restrict__ W12,
                            ushort_t* __restrict__ xb, uchar_t* __restrict__ xf8,
                            ushort_t* __restrict__ w1t, uchar_t* __restrict__ w2t8) {
    if (blockIdx.x < DEG_BLOCKS) {
        int grp = blockIdx.x & 7;
        int slice = blockIdx.x >> 3;
        int dlo = grp * DRANGE;
        int dhi = min(dlo + DRANGE, N_NODES);
        int base = slice * EPB + threadIdx.x;
        #pragma unroll
        for (int i = 0; i < EPT; ++i) {
            int e = base + i * 256;
            if (e < N_EDGES) {
                int dst = edge[N_EDGES + e];
                if (dst >= dlo && dst < dhi) atomicAdd(deg + dst, 1);
            }
        }
    } else {
        int tid = (blockIdx.x - DEG_BLOCKS) * 256 + threadIdx.x;
        if (tid < N_NODES * 32) {
            int row = tid >> 5, c = (tid & 31) * 4;
            float4 v = *(const float4*)(x + (size_t)row * FEAT + c);
            ushort4 o;
            o.x = f2b(v.x); o.y = f2b(v.y); o.z = f2b(v.z); o.w = f2b(v.w);
            *(ushort4*)(xb + (size_t)row * (2 * FEAT) + c) = o;
            *(uint32*)(xf8 + (size_t)row * FEAT + c) = pk4f8(v.x, v.y, v.z, v.w);
        } else if (tid < N_NODES * 32 + 256 * 256) {
            int t1 = tid - N_NODES * 32;
            int n = t1 >> 8, k = t1 & 255;
            float v = (k < 128) ? W01[(size_t)k * 256 + n] : W11[(size_t)(k - 128) * 256 + n];
            w1t[t1] = f2b(v);
        } else {
            int t2 = tid - N_NODES * 32 - 256 * 256;
            int n = t2 >> 9, k = t2 & 511;
            float v = (k < 256) ? W02[(size_t)k * 512 + n] : W12[(size_t)(k - 256) * 512 + n];
            w2t8[t2] = f2f8(v);
        }
    }
}

// ---- 2-phase scan ----
__global__ __launch_bounds__(SCAN_B) void scan_part_kernel(const int* __restrict__ deg,
                                                           int* __restrict__ blocksum) {
    __shared__ int s[SCAN_B];
    int i = blockIdx.x * SCAN_B + threadIdx.x;
    int t = threadIdx.x;
    s[t] = (i < N_NODES) ? deg[i] : 0;
    __syncthreads();
    #pragma unroll
    for (int off = SCAN_B / 2; off > 0; off >>= 1) {
        if (t < off) s[t] += s[t + off];
        __syncthreads();
    }
    if (t == 0) blocksum[blockIdx.x] = s[0];
}

__global__ __launch_bounds__(SCAN_B) void scan_final_kernel(const int* __restrict__ deg,
                                                            const int* __restrict__ blocksum,
                                                            int* __restrict__ offsets,
                                                            int* __restrict__ cursor,
                                                            float* __restrict__ rinv,
                                                            const int* __restrict__ batch,
                                                            float* __restrict__ ncnt) {
    __shared__ int bs_[SCAN_B];
    __shared__ int s[SCAN_B];
    int t = threadIdx.x;
    int bv = (t < SCAN_NB) ? blocksum[t] : 0;
    bs_[t] = bv;
    __syncthreads();
    #pragma unroll
    for (int off = 1; off < SCAN_B; off <<= 1) {
        int u = (t >= off) ? bs_[t - off] : 0;
        __syncthreads();
        bs_[t] += u;
        __syncthreads();
    }
    int base = (blockIdx.x == 0) ? 0 : bs_[blockIdx.x - 1];

    int i = blockIdx.x * SCAN_B + t;
    int v = (i < N_NODES) ? deg[i] : 0;
    s[t] = v;
    __syncthreads();
    #pragma unroll
    for (int off = 1; off < SCAN_B; off <<= 1) {
        int u = (t >= off) ? s[t - off] : 0;
        __syncthreads();
        s[t] += u;
        __syncthreads();
    }
    int excl = s[t] - v + base;
    if (i < N_NODES) {
        offsets[i] = excl;
        cursor[i] = excl;
        rinv[i] = 1.0f / (float)max(v, 1);
    }
    if (i == N_NODES - 1) offsets[N_NODES] = excl + v;

    if (blockIdx.x == 0 && t < N_GRAPHS) {
        int g = t;
        int lo = 0, hi = N_NODES;
        while (lo < hi) { int mid = (lo + hi) >> 1; if (batch[mid] < g) lo = mid + 1; else hi = mid; }
        int lo2 = lo, hi2 = N_NODES;
        while (lo2 < hi2) { int mid = (lo2 + hi2) >> 1; if (batch[mid] < g + 1) lo2 = mid + 1; else hi2 = mid; }
        ncnt[g] = (float)(lo2 - lo);
    }
}

__global__ void fill_kernel(const int* __restrict__ edge,
                            int* __restrict__ cursor, int* __restrict__ srcbuf) {
    int grp = blockIdx.x & 7;
    int slice = blockIdx.x >> 3;
    int dlo = grp * DRANGE;
    int dhi = min(dlo + DRANGE, N_NODES);
    int base = slice * EPB + threadIdx.x;
    #pragma unroll
    for (int i = 0; i < EPT; ++i) {
        int e = base + i * 256;
        if (e < N_EDGES) {
            int dst = edge[N_EDGES + e];
            if (dst >= dlo && dst < dhi) {
                int pos = atomicAdd(cursor + dst, 1);
                srcbuf[pos] = edge[e];
            }
        }
    }
}

// ---------------- CSR gathers ----------------
// gather1: fp8 source (128 B/row); 8 lane-groups of 8 -> 8 edges per instruction
__global__ __launch_bounds__(256) void gather1_kernel(
    const int* __restrict__ offsets, const int* __restrict__ srcbuf,
    const float* __restrict__ rinv, const uchar_t* __restrict__ xf8,
    ushort_t* __restrict__ xb)
{
    int node = blockIdx.x * 4 + (threadIdx.x >> 6);
    if (node >= N_NODES) return;
    int lane = threadIdx.x & 63;
    int grp = lane >> 3;
    int l8 = lane & 7;
    int beg = offsets[node], end = offsets[node + 1];

    float a[16];
    #pragma unroll
    for (int k = 0; k < 16; ++k) a[k] = 0.f;

    int j = beg + grp;
    for (; j + 8 < end; j += 16) {
        int s0 = srcbuf[j];
        int s1 = srcbuf[j + 8];
        uint4 u0 = *(const uint4*)(xf8 + (size_t)s0 * FEAT + l8 * 16);
        uint4 u1 = *(const uint4*)(xf8 + (size_t)s1 * FEAT + l8 * 16);
        accf8(u0.x, a + 0); accf8(u0.y, a + 4); accf8(u0.z, a + 8); accf8(u0.w, a + 12);
        accf8(u1.x, a + 0); accf8(u1.y, a + 4); accf8(u1.z, a + 8); accf8(u1.w, a + 12);
    }
    for (; j < end; j += 8) {
        int s0 = srcbuf[j];
        uint4 u0 = *(const uint4*)(xf8 + (size_t)s0 * FEAT + l8 * 16);
        accf8(u0.x, a + 0); accf8(u0.y, a + 4); accf8(u0.z, a + 8); accf8(u0.w, a + 12);
    }
    #pragma unroll
    for (int k = 0; k < 16; ++k) a[k] += __shfl_down(a[k], 32);
    #pragma unroll
    for (int k = 0; k < 16; ++k) a[k] += __shfl_down(a[k], 16);
    #pragma unroll
    for (int k = 0; k < 16; ++k) a[k] += __shfl_down(a[k], 8);
    if (grp == 0) {
        float ri = rinv[node];
        uint4 o0, o1;
        o0.x = (uint32)f2b(a[0] * ri)  | ((uint32)f2b(a[1] * ri) << 16);
        o0.y = (uint32)f2b(a[2] * ri)  | ((uint32)f2b(a[3] * ri) << 16);
        o0.z = (uint32)f2b(a[4] * ri)  | ((uint32)f2b(a[5] * ri) << 16);
        o0.w = (uint32)f2b(a[6] * ri)  | ((uint32)f2b(a[7] * ri) << 16);
        o1.x = (uint32)f2b(a[8] * ri)  | ((uint32)f2b(a[9] * ri) << 16);
        o1.y = (uint32)f2b(a[10] * ri) | ((uint32)f2b(a[11] * ri) << 16);
        o1.z = (uint32)f2b(a[12] * ri) | ((uint32)f2b(a[13] * ri) << 16);
        o1.w = (uint32)f2b(a[14] * ri) | ((uint32)f2b(a[15] * ri) << 16);
        *(uint4*)(xb + (size_t)node * 256 + 128 + l8 * 16) = o0;
        *(uint4*)(xb + (size_t)node * 256 + 128 + l8 * 16 + 8) = o1;
    }
}

// gather2: fp8 in/out on h1a8[50000][512] (cols 0..255 = h1 fp8, 256..511 = agg2 fp8)
__global__ __launch_bounds__(256) void gather2_kernel(
    const int* __restrict__ offsets, const int* __restrict__ srcbuf,
    const float* __restrict__ rinv, uchar_t* __restrict__ h1a8)
{
    int node = blockIdx.x * 4 + (threadIdx.x >> 6);
    if (node >= N_NODES) return;
    int lane = threadIdx.x & 63;
    int grp = lane >> 4;
    int l16 = lane & 15;
    int beg = offsets[node], end = offsets[node + 1];

    float a[16];
    #pragma unroll
    for (int k = 0; k < 16; ++k) a[k] = 0.f;

    int j = beg + grp;
    for (; j + 4 < end; j += 8) {
        int s0 = srcbuf[j];
        int s1 = srcbuf[j + 4];
        uint4 u0 = *(const uint4*)(h1a8 + (size_t)s0 * 512 + l16 * 16);
        uint4 u1 = *(const uint4*)(h1a8 + (size_t)s1 * 512 + l16 * 16);
        accf8(u0.x, a + 0); accf8(u0.y, a + 4); accf8(u0.z, a + 8); accf8(u0.w, a + 12);
        accf8(u1.x, a + 0); accf8(u1.y, a + 4); accf8(u1.z, a + 8); accf8(u1.w, a + 12);
    }
    for (; j < end; j += 4) {
        int s0 = srcbuf[j];
        uint4 u0 = *(const uint4*)(h1a8 + (size_t)s0 * 512 + l16 * 16);
        accf8(u0.x, a + 0); accf8(u0.y, a + 4); accf8(u0.z, a + 8); accf8(u0.w, a + 12);
    }
    #pragma unroll
    for (int k = 0; k < 16; ++k) a[k] += __shfl_down(a[k], 32);
    #pragma unroll
    for (int k = 0; k < 16; ++k) a[k] += __shfl_down(a[k], 16);
    if (grp == 0) {
        float ri = rinv[node];
        uint4 o;
        o.x = pk4f8(a[0] * ri,  a[1] * ri,  a[2] * ri,  a[3] * ri);
        o.y = pk4f8(a[4] * ri,  a[5] * ri,  a[6] * ri,  a[7] * ri);
        o.z = pk4f8(a[8] * ri,  a[9] * ri,  a[10] * ri, a[11] * ri);
        o.w = pk4f8(a[12] * ri, a[13] * ri, a[14] * ri, a[15] * ri);
        *(uint4*)(h1a8 + (size_t)node * 512 + 256 + l16 * 16) = o;
    }
}

// ---------------- bf16 MFMA GEMM (layer 1: 128x128 tile, BK=64, fp8-only output) ----------------
template<int KTOT, int F8STR, int COLS>
__global__ __launch_bounds__(256) void mfma_gemm_bf16(
    const ushort_t* __restrict__ A, const ushort_t* __restrict__ Bt,
    const float* __restrict__ bias, uchar_t* __restrict__ outf8)
{
    __shared__ ushort_t As[8192];
    __shared__ ushort_t Bs[8192];

    const int id = blockIdx.x;
    const int xcd = id & 7;
    const int s_ = id >> 3;
    const int col = s_ & (COLS - 1);
    const int rloc = s_ / COLS;
    const int rowblk = xcd * RPX + rloc;
    if (rowblk >= RB) return;

    const int tid = threadIdx.x;
    const int lane = tid & 63;
    const int wave = tid >> 6;
    const int quad = lane >> 4;
    const int l16 = lane & 15;
    const int m0w = (wave & 1) * 64;
    const int n0w = (wave >> 1) * 64;
    const int row0 = rowblk * 128;
    const int col0 = col * 128;
    const int Mm1 = N_NODES - 1;

    int st_r[4], st_q[4];
    #pragma unroll
    for (int c = 0; c < 4; ++c) {
        int slot = c * 256 + tid;
        int r = slot >> 3;
        st_r[c] = r;
        st_q[c] = ((slot & 7) ^ (r & 7)) * 8;
    }

    floatx4 acc[4][4] = {};

    for (int kt = 0; kt < KTOT / 64; ++kt) {
        const int kb = kt * 64;
        #pragma unroll
        for (int c = 0; c < 4; ++c) {
            async16(A + (size_t)min(row0 + st_r[c], Mm1) * KTOT + kb + st_q[c],
                    &As[(c * 256 + wave * 64) * 8]);
        }
        #pragma unroll
        for (int c = 0; c < 4; ++c) {
            async16(Bt + (size_t)(col0 + st_r[c]) * KTOT + kb + st_q[c],
                    &Bs[(c * 256 + wave * 64) * 8]);
        }
        __syncthreads();
        #pragma unroll
        for (int kk = 0; kk < 2; ++kk) {
            short8 a[4], b[4];
            #pragma unroll
            for (int t = 0; t < 4; ++t) {
                int r = m0w + t * 16 + l16;
                a[t] = *(const short8*)&As[r * 64 + (((kk * 4 + quad) ^ (r & 7)) * 8)];
            }
            #pragma unroll
            for (int t = 0; t < 4; ++t) {
                int r = n0w + t * 16 + l16;
                b[t] = *(const short8*)&Bs[r * 64 + (((kk * 4 + quad) ^ (r & 7)) * 8)];
            }
            #pragma unroll
            for (int i = 0; i < 4; ++i)
                #pragma unroll
                for (int j = 0; j < 4; ++j)
                    acc[i][j] = __builtin_amdgcn_mfma_f32_16x16x32_bf16(a[i], b[j], acc[i][j], 0, 0, 0);
        }
        __syncthreads();
    }

    float bias4[4];
    #pragma unroll
    for (int j = 0; j < 4; ++j) bias4[j] = bias[col0 + n0w + j * 16 + l16];

    #pragma unroll
    for (int i = 0; i < 4; ++i) {
        #pragma unroll
        for (int r = 0; r < 4; ++r) {
            int m = row0 + m0w + i * 16 + quad * 4 + r;
            if (m < N_NODES) {
                #pragma unroll
                for (int j = 0; j < 4; ++j) {
                    float v = fmaxf(acc[i][j][r] + bias4[j], 0.f);
                    outf8[(size_t)m * F8STR + col0 + n0w + j * 16 + l16] = f2f8(v);
                }
            }
        }
    }
}

// ---------------- fp8 MFMA GEMM (layer 2: 128x128 tile, BK=128 fp8, pooled) ----------------
// A/B fp8 e4m3 (A row = KTOT bytes); 16x16x32_fp8_fp8 MFMA (long operands).
template<int KTOT, int COLS>
__global__ __launch_bounds__(256) void mfma_gemm_f8(
    const uchar_t* __restrict__ A, const uchar_t* __restrict__ Bt,
    const float* __restrict__ bias,
    float* __restrict__ psum, const int* __restrict__ batch)
{
    __shared__ uchar_t As[16384];       // 128 rows x 128 B (BK=128)
    __shared__ uchar_t Bs[16384];
    __shared__ float pool2[8 * 128];

    const int id = blockIdx.x;
    const int xcd = id & 7;
    const int s_ = id >> 3;
    const int col = s_ & (COLS - 1);
    const int rloc = s_ / COLS;
    const int rowblk = xcd * RPX + rloc;
    if (rowblk >= RB) return;

    const int tid = threadIdx.x;
    const int lane = tid & 63;
    const int wave = tid >> 6;
    const int quad = lane >> 4;
    const int l16 = lane & 15;
    const int m0w = (wave & 1) * 64;
    const int n0w = (wave >> 1) * 64;
    const int row0 = rowblk * 128;
    const int col0 = col * 128;
    const int Mm1 = N_NODES - 1;

    // staging: 1024 slots of 16B per buffer; slot -> row r = slot>>3, chunk q = slot&7 at q^(r&7)
    int st_r[4], st_q[4];
    #pragma unroll
    for (int c = 0; c < 4; ++c) {
        int slot = c * 256 + tid;
        int r = slot >> 3;
        st_r[c] = r;
        st_q[c] = ((slot & 7) ^ (r & 7)) * 16;   // byte offset
    }

    floatx4 acc[4][4] = {};

    for (int kt = 0; kt < KTOT / 128; ++kt) {
        const int kb = kt * 128;
        #pragma unroll
        for (int c = 0; c < 4; ++c) {
            async16(A + (size_t)min(row0 + st_r[c], Mm1) * KTOT + kb + st_q[c],
                    &As[(c * 256 + wave * 64) * 16]);
        }
        #pragma unroll
        for (int c = 0; c < 4; ++c) {
            async16(Bt + (size_t)(col0 + st_r[c]) * KTOT + kb + st_q[c],
                    &Bs[(c * 256 + wave * 64) * 16]);
        }
        __syncthreads();
        #pragma unroll
        for (int kk = 0; kk < 4; ++kk) {       // 4 x K=32 MFMA windows
            const int c0 = kk * 2 + (quad >> 1);
            const int o8 = (quad & 1) * 8;
            long a[4], b[4];
            #pragma unroll
            for (int t = 0; t < 4; ++t) {
                int r = m0w + t * 16 + l16;
                a[t] = *(const long*)&As[r * 128 + ((c0 ^ (r & 7)) * 16) + o8];
            }
            #pragma unroll
            for (int t = 0; t < 4; ++t) {
                int r = n0w + t * 16 + l16;
                b[t] = *(const long*)&Bs[r * 128 + ((c0 ^ (r & 7)) * 16) + o8];
            }
            #pragma unroll
            for (int i = 0; i < 4; ++i)
                #pragma unroll
                for (int j = 0; j < 4; ++j)
                    acc[i][j] = __builtin_amdgcn_mfma_f32_16x16x32_fp8_fp8(a[i], b[j], acc[i][j], 0, 0, 0);
        }
        __syncthreads();
    }

    float bias4[4];
    #pragma unroll
    for (int j = 0; j < 4; ++j) bias4[j] = bias[col0 + n0w + j * 16 + l16];

    int gmin = batch[row0];
    int gmax = batch[min(row0 + 127, N_NODES - 1)];
    int span = gmax - gmin + 1;
    if (span == 1) {
        float s[4] = {0.f, 0.f, 0.f, 0.f};
        #pragma unroll
        for (int i = 0; i < 4; ++i) {
            #pragma unroll
            for (int r = 0; r < 4; ++r) {
                int m = row0 + m0w + i * 16 + quad * 4 + r;
                if (m < N_NODES) {
                    #pragma unroll
                    for (int j = 0; j < 4; ++j)
                        s[j] += fmaxf(acc[i][j][r] + bias4[j], 0.f);
                }
            }
        }
        int slot = (wave & 1) * 4 + quad;
        #pragma unroll
        for (int j = 0; j < 4; ++j)
            pool2[slot * 128 + n0w + j * 16 + l16] = s[j];
        __syncthreads();
        if (tid < 128) {
            float v = 0.f;
            #pragma unroll
            for (int k = 0; k < 8; ++k) v += pool2[k * 128 + tid];
            atomicAdd(psum + (size_t)gmin * HID + col0 + tid, v);
        }
    } else if (span <= 8) {
        for (int i = tid; i < span * 128; i += 256) pool2[i] = 0.f;
        __syncthreads();
        float s[4] = {0.f, 0.f, 0.f, 0.f};
        int cg = -1;
        #pragma unroll
        for (int i = 0; i < 4; ++i) {
            #pragma unroll
            for (int r = 0; r < 4; ++r) {
                int m = row0 + m0w + i * 16 + quad * 4 + r;
                if (m < N_NODES) {
                    int g = batch[m] - gmin;
                    if (g != cg) {
                        if (cg >= 0) {
                            #pragma unroll
                            for (int j = 0; j < 4; ++j)
                                atomicAdd(&pool2[cg * 128 + n0w + j * 16 + l16], s[j]);
                        }
                        cg = g;
                        s[0] = s[1] = s[2] = s[3] = 0.f;
                    }
                    #pragma unroll
                    for (int j = 0; j < 4; ++j)
                        s[j] += fmaxf(acc[i][j][r] + bias4[j], 0.f);
                }
            }
        }
        if (cg >= 0) {
            #pragma unroll
            for (int j = 0; j < 4; ++j)
                atomicAdd(&pool2[cg * 128 + n0w + j * 16 + l16], s[j]);
        }
        __syncthreads();
        for (int i = tid; i < span * 128; i += 256) {
            float v = pool2[i];
            if (v != 0.f)
                atomicAdd(psum + (size_t)(gmin + (i >> 7)) * HID + col0 + (i & 127), v);
        }
    } else {
        #pragma unroll
        for (int i = 0; i < 4; ++i) {
            #pragma unroll
            for (int r = 0; r < 4; ++r) {
                int m = row0 + m0w + i * 16 + quad * 4 + r;
                if (m < N_NODES) {
                    int g = batch[m];
                    #pragma unroll
                    for (int j = 0; j < 4; ++j) {
                        float v = fmaxf(acc[i][j][r] + bias4[j], 0.f);
                        atomicAdd(psum + (size_t)g * HID + col0 + n0w + j * 16 + l16, v);
                    }
                }
            }
        }
    }
}

// ---------------- head ----------------
__global__ __launch_bounds__(64) void head_hc_kernel(
    const float* __restrict__ psum, const float* __restrict__ ncnt,
    const float* __restrict__ Wh, const float* __restrict__ bh,
    const float* __restrict__ Wc, const float* __restrict__ bc,
    float* __restrict__ out)
{
    __shared__ float p[HID];
    const int tile = blockIdx.x, g = blockIdx.y, t = threadIdx.x;
    float inv = 1.0f / fmaxf(ncnt[g], 1.0f);
    #pragma unroll
    for (int i = 0; i < 8; ++i)
        p[i * 64 + t] = psum[(size_t)g * HID + i * 64 + t] * inv;
    __syncthreads();
    int col = tile * 64 + t;
    float h = bh[col], c = bc[col];
    #pragma unroll 8
    for (int k = 0; k < HID; ++k) {
        float pk = p[k];
        h += pk * Wh[(size_t)k * HID + col];
        c += pk * Wc[(size_t)k * HID + col];
    }
    out[(size_t)N_GRAPHS * VOCAB + (size_t)g * HID + col] = h;       // hidden
    out[(size_t)2 * N_GRAPHS * VOCAB + (size_t)g * HID + col] = c;   // cell
}

__global__ __launch_bounds__(512) void head_out_kernel(
    const float* __restrict__ hidden, const float* __restrict__ Wout,
    const float* __restrict__ bout, float* __restrict__ out)
{
    __shared__ float hrow[HID];
    __shared__ float redm[8];
    __shared__ float reds[8];
    __shared__ float bm, bs;
    const int g = blockIdx.x, j = threadIdx.x;
    hrow[j] = hidden[(size_t)g * HID + j];
    __syncthreads();
    float l = bout[j];
    #pragma unroll 8
    for (int k = 0; k < HID; ++k)
        l += hrow[k] * Wout[(size_t)k * VOCAB + j];

    const int lane = j & 63, wave = j >> 6;
    float m = l;
    #pragma unroll
    for (int o = 32; o > 0; o >>= 1) m = fmaxf(m, __shfl_down(m, o));
    if (lane == 0) redm[wave] = m;
    __syncthreads();
    if (j == 0) {
        float mm = redm[0];
        for (int w = 1; w < 8; ++w) mm = fmaxf(mm, redm[w]);
        bm = mm;
    }
    __syncthreads();
    m = bm;
    float e = __expf(l - m);
    float s = e;
    #pragma unroll
    for (int o = 32; o > 0; o >>= 1) s += __shfl_down(s, o);
    if (lane == 0) reds[wave] = s;
    __syncthreads();
    if (j == 0) {
        float ss = 0.f;
        for (int w = 0; w < 8; ++w) ss += reds[w];
        bs = ss;
    }
    __syncthreads();
    out[(size_t)g * VOCAB + j] = l - m - logf(bs);                  // logits
}

// ---------------- launch ----------------
extern "C" void kernel_launch(void* const* d_in, const int* in_sizes, int n_in,
                              void* d_out, int out_size, void* d_ws, size_t ws_size,
                              hipStream_t stream) {
    const float* x      = (const float*)d_in[1];
    const int*   edge   = (const int*)d_in[2];
    const int*   batch  = (const int*)d_in[3];
    const float* Wroot1 = (const float*)d_in[4];
    const float* Wrel1  = (const float*)d_in[5];
    const float* b1     = (const float*)d_in[6];
    const float* Wroot2 = (const float*)d_in[7];
    const float* Wrel2  = (const float*)d_in[8];
    const float* b2     = (const float*)d_in[9];
    const float* Wh     = (const float*)d_in[10];
    const float* bh     = (const float*)d_in[11];
    const float* Wc     = (const float*)d_in[12];
    const float* bc     = (const float*)d_in[13];
    const float* Wout   = (const float*)d_in[14];
    const float* bout   = (const float*)d_in[15];
    float* out = (float*)d_out;

    // workspace layout: deg+psum first (single minimal memset)
    int*      deg_i   = (int*)d_ws;                        // 50000 (zeroed)
    float*    psum    = (float*)(deg_i + N_NODES);         // 32768 (zeroed)
    int*      cursor  = (int*)(psum + N_GRAPHS * HID);     // 50000 (init by scan_final)
    float*    ncnt    = (float*)(cursor + N_NODES);        // 64
    int*      offsets = (int*)(ncnt + N_GRAPHS);           // 50001
    int*      srcbuf  = offsets + (N_NODES + 1);           // 800000
    int*      bsum    = srcbuf + N_EDGES;                  // 256
    int*      pad_    = bsum + 256;                        // 256
    float*    rinv    = (float*)(pad_ + 256);              // 50000 (+3 pad)
    ushort_t* xb      = (ushort_t*)(rinv + N_NODES + 3);   // 50000*256 bf16
    ushort_t* w1t     = xb + (size_t)N_NODES * 256;        // 256*256 bf16
    uchar_t*  h1a8    = (uchar_t*)(w1t + 256 * 256);       // 50000*512 fp8
    uchar_t*  w2t8    = h1a8 + (size_t)N_NODES * 512;      // 512*512 fp8
    uchar_t*  xf8     = w2t8 + 512 * 512;                  // 50000*128 fp8

    hipMemsetAsync(d_ws, 0, (size_t)(N_NODES + N_GRAPHS * HID) * 4, stream);

    prep_kernel<<<DEG_BLOCKS + CONV_BLOCKS, 256, 0, stream>>>(
        edge, deg_i, x, Wroot1, Wrel1, Wroot2, Wrel2, xb, xf8, w1t, w2t8);
    scan_part_kernel<<<SCAN_NB, SCAN_B, 0, stream>>>(deg_i, bsum);
    scan_final_kernel<<<SCAN_NB, SCAN_B, 0, stream>>>(
        deg_i, bsum, offsets, cursor, rinv, batch, ncnt);
    fill_kernel<<<8 * NBF, 256, 0, stream>>>(edge, cursor, srcbuf);

    gather1_kernel<<<(N_NODES + 3) / 4, 256, 0, stream>>>(offsets, srcbuf, rinv, xf8, xb);

    {   // layer 1: A=xb [50000 x 256] bf16 -> h1a8 cols 0..255 (fp8 only); COLS=2
        mfma_gemm_bf16<256, 512, 2><<<8 * RPX * 2, 256, 0, stream>>>(
            xb, w1t, b1, h1a8);
    }

    gather2_kernel<<<(N_NODES + 3) / 4, 256, 0, stream>>>(offsets, srcbuf, rinv, h1a8);

    {   // layer 2: A=h1a8 [50000 x 512] fp8, B=w2t8 fp8 -> pooled psum; COLS=4
        mfma_gemm_f8<512, 4><<<8 * RPX * 4, 256, 0, stream>>>(
            h1a8, w2t8, b2, psum, batch);
    }

    head_hc_kernel<<<dim3(8, 64), 64, 0, stream>>>(psum, ncnt, Wh, bh, Wc, bc, out);
    head_out_kernel<<<N_GRAPHS, 512, 0, stream>>>(
        out + (size_t)N_GRAPHS * VOCAB, Wout, bout, out);
}

// Round 17
// 368.074 us; speedup vs baseline: 1.2146x; 1.0194x over previous
//
#include <hip/hip_runtime.h>
#include <hip/hip_bf16.h>

#define N_NODES 50000
#define N_EDGES 800000
#define N_GRAPHS 64
#define FEAT 128
#define EMB 256
#define HID 512
#define VOCAB 512

#define SCAN_B 256
#define SCAN_NB ((N_NODES + SCAN_B - 1) / SCAN_B)   // 196
#define RB ((N_NODES + 127) / 128)                  // 391 row-blocks
#define RPX ((RB + 7) / 8)                          // 49 row-blocks per XCD
#define DRANGE ((N_NODES + 7) / 8)                  // 6250 dst per partition
#define EPT 8                                       // edges/thread in deg/fill
#define EPB (256 * EPT)                             // 2048 edges/block
#define NBF ((N_EDGES + EPB - 1) / EPB)             // 391 slices
#define DEG_BLOCKS (8 * NBF)                        // 3128
#define CONV_ELEMS (N_NODES * 32 + 256 * 256 + 512 * 512)  // 1,927,680
#define CONV_BLOCKS (CONV_ELEMS / 256)              // 7530

typedef __attribute__((ext_vector_type(4))) float floatx4;
typedef __attribute__((ext_vector_type(2))) float floatx2;
typedef unsigned short ushort_t;
typedef unsigned int uint32;
typedef unsigned char uchar_t;

__device__ __forceinline__ ushort_t f2b(float f) {
    uint32 u = __builtin_bit_cast(uint32, f);
    u += 0x7fffu + ((u >> 16) & 1u);
    return (ushort_t)(u >> 16);
}
// u holds 4 fp8 e4m3; accumulate into a[0..3]
__device__ __forceinline__ void accf8(uint32 u, float* a) {
    floatx2 lo = __builtin_amdgcn_cvt_pk_f32_fp8(u, false);
    floatx2 hi = __builtin_amdgcn_cvt_pk_f32_fp8(u, true);
    a[0] += lo[0]; a[1] += lo[1]; a[2] += hi[0]; a[3] += hi[1];
}
__device__ __forceinline__ uchar_t f2f8(float v) {
    return (uchar_t)(__builtin_amdgcn_cvt_pk_fp8_f32(v, v, 0, false) & 0xff);
}
__device__ __forceinline__ uint32 pk4f8(float a, float b, float c, float d) {
    uint32 w = __builtin_amdgcn_cvt_pk_fp8_f32(a, b, 0, false);
    return __builtin_amdgcn_cvt_pk_fp8_f32(c, d, w, true);
}
__device__ __forceinline__ void async16(const void* g, void* l) {
    __builtin_amdgcn_global_load_lds(
        (const __attribute__((address_space(1))) void*)g,
        (__attribute__((address_space(3))) void*)l, 16, 0, 0);
}

// ---------------- prep: deg histogram (dst-partitioned) + all converts ----------------
__global__ void prep_kernel(const int* __restrict__ edge, int* __restrict__ deg,
                            const float* __restrict__ x,
                            const float* __restrict__ W01, const float* __restrict__ W11,
                            const float* __restrict__ W02, const float* __restrict__ W12,
                            uchar_t* __restrict__ xa8,
                            uchar_t* __restrict__ w1t8, uchar_t* __restrict__ w2t8) {
    if (blockIdx.x < DEG_BLOCKS) {
        int grp = blockIdx.x & 7;
        int slice = blockIdx.x >> 3;
        int dlo = grp * DRANGE;
        int dhi = min(dlo + DRANGE, N_NODES);
        int base = slice * EPB + threadIdx.x;
        #pragma unroll
        for (int i = 0; i < EPT; ++i) {
            int e = base + i * 256;
            if (e < N_EDGES) {
                int dst = edge[N_EDGES + e];
                if (dst >= dlo && dst < dhi) atomicAdd(deg + dst, 1);
            }
        }
    } else {
        int tid = (blockIdx.x - DEG_BLOCKS) * 256 + threadIdx.x;
        if (tid < N_NODES * 32) {
            int row = tid >> 5, c = (tid & 31) * 4;
            float4 v = *(const float4*)(x + (size_t)row * FEAT + c);
            *(uint32*)(xa8 + (size_t)row * 256 + c) = pk4f8(v.x, v.y, v.z, v.w);
        } else if (tid < N_NODES * 32 + 256 * 256) {
            int t1 = tid - N_NODES * 32;
            int n = t1 >> 8, k = t1 & 255;
            float v = (k < 128) ? W01[(size_t)k * 256 + n] : W11[(size_t)(k - 128) * 256 + n];
            w1t8[t1] = f2f8(v);
        } else {
            int t2 = tid - N_NODES * 32 - 256 * 256;
            int n = t2 >> 9, k = t2 & 511;
            float v = (k < 256) ? W02[(size_t)k * 512 + n] : W12[(size_t)(k - 256) * 512 + n];
            w2t8[t2] = f2f8(v);
        }
    }
}

// ---- 2-phase scan ----
__global__ __launch_bounds__(SCAN_B) void scan_part_kernel(const int* __restrict__ deg,
                                                           int* __restrict__ blocksum) {
    __shared__ int s[SCAN_B];
    int i = blockIdx.x * SCAN_B + threadIdx.x;
    int t = threadIdx.x;
    s[t] = (i < N_NODES) ? deg[i] : 0;
    __syncthreads();
    #pragma unroll
    for (int off = SCAN_B / 2; off > 0; off >>= 1) {
        if (t < off) s[t] += s[t + off];
        __syncthreads();
    }
    if (t == 0) blocksum[blockIdx.x] = s[0];
}

__global__ __launch_bounds__(SCAN_B) void scan_final_kernel(const int* __restrict__ deg,
                                                            const int* __restrict__ blocksum,
                                                            int* __restrict__ offsets,
                                                            int* __restrict__ cursor,
                                                            float* __restrict__ rinv,
                                                            const int* __restrict__ batch,
                                                            float* __restrict__ ncnt) {
    __shared__ int bs_[SCAN_B];
    __shared__ int s[SCAN_B];
    int t = threadIdx.x;
    int bv = (t < SCAN_NB) ? blocksum[t] : 0;
    bs_[t] = bv;
    __syncthreads();
    #pragma unroll
    for (int off = 1; off < SCAN_B; off <<= 1) {
        int u = (t >= off) ? bs_[t - off] : 0;
        __syncthreads();
        bs_[t] += u;
        __syncthreads();
    }
    int base = (blockIdx.x == 0) ? 0 : bs_[blockIdx.x - 1];

    int i = blockIdx.x * SCAN_B + t;
    int v = (i < N_NODES) ? deg[i] : 0;
    s[t] = v;
    __syncthreads();
    #pragma unroll
    for (int off = 1; off < SCAN_B; off <<= 1) {
        int u = (t >= off) ? s[t - off] : 0;
        __syncthreads();
        s[t] += u;
        __syncthreads();
    }
    int excl = s[t] - v + base;
    if (i < N_NODES) {
        offsets[i] = excl;
        cursor[i] = excl;
        rinv[i] = 1.0f / (float)max(v, 1);
    }
    if (i == N_NODES - 1) offsets[N_NODES] = excl + v;

    if (blockIdx.x == 0 && t < N_GRAPHS) {
        int g = t;
        int lo = 0, hi = N_NODES;
        while (lo < hi) { int mid = (lo + hi) >> 1; if (batch[mid] < g) lo = mid + 1; else hi = mid; }
        int lo2 = lo, hi2 = N_NODES;
        while (lo2 < hi2) { int mid = (lo2 + hi2) >> 1; if (batch[mid] < g + 1) lo2 = mid + 1; else hi2 = mid; }
        ncnt[g] = (float)(lo2 - lo);
    }
}

__global__ void fill_kernel(const int* __restrict__ edge,
                            int* __restrict__ cursor, int* __restrict__ srcbuf) {
    int grp = blockIdx.x & 7;
    int slice = blockIdx.x >> 3;
    int dlo = grp * DRANGE;
    int dhi = min(dlo + DRANGE, N_NODES);
    int base = slice * EPB + threadIdx.x;
    #pragma unroll
    for (int i = 0; i < EPT; ++i) {
        int e = base + i * 256;
        if (e < N_EDGES) {
            int dst = edge[N_EDGES + e];
            if (dst >= dlo && dst < dhi) {
                int pos = atomicAdd(cursor + dst, 1);
                srcbuf[pos] = edge[e];
            }
        }
    }
}

// ---------------- CSR gathers ----------------
// gather1: fp8 in/out on xa8[50000][256] (cols 0..127 = x fp8, 128..255 = agg1 fp8)
__global__ __launch_bounds__(256) void gather1_kernel(
    const int* __restrict__ offsets, const int* __restrict__ srcbuf,
    const float* __restrict__ rinv, uchar_t* __restrict__ xa8)
{
    int node = blockIdx.x * 4 + (threadIdx.x >> 6);
    if (node >= N_NODES) return;
    int lane = threadIdx.x & 63;
    int grp = lane >> 3;
    int l8 = lane & 7;
    int beg = offsets[node], end = offsets[node + 1];

    float a[16];
    #pragma unroll
    for (int k = 0; k < 16; ++k) a[k] = 0.f;

    int j = beg + grp;
    for (; j + 8 < end; j += 16) {
        int s0 = srcbuf[j];
        int s1 = srcbuf[j + 8];
        uint4 u0 = *(const uint4*)(xa8 + (size_t)s0 * 256 + l8 * 16);
        uint4 u1 = *(const uint4*)(xa8 + (size_t)s1 * 256 + l8 * 16);
        accf8(u0.x, a + 0); accf8(u0.y, a + 4); accf8(u0.z, a + 8); accf8(u0.w, a + 12);
        accf8(u1.x, a + 0); accf8(u1.y, a + 4); accf8(u1.z, a + 8); accf8(u1.w, a + 12);
    }
    for (; j < end; j += 8) {
        int s0 = srcbuf[j];
        uint4 u0 = *(const uint4*)(xa8 + (size_t)s0 * 256 + l8 * 16);
        accf8(u0.x, a + 0); accf8(u0.y, a + 4); accf8(u0.z, a + 8); accf8(u0.w, a + 12);
    }
    #pragma unroll
    for (int k = 0; k < 16; ++k) a[k] += __shfl_down(a[k], 32);
    #pragma unroll
    for (int k = 0; k < 16; ++k) a[k] += __shfl_down(a[k], 16);
    #pragma unroll
    for (int k = 0; k < 16; ++k) a[k] += __shfl_down(a[k], 8);
    if (grp == 0) {
        float ri = rinv[node];
        uint4 o;
        o.x = pk4f8(a[0] * ri,  a[1] * ri,  a[2] * ri,  a[3] * ri);
        o.y = pk4f8(a[4] * ri,  a[5] * ri,  a[6] * ri,  a[7] * ri);
        o.z = pk4f8(a[8] * ri,  a[9] * ri,  a[10] * ri, a[11] * ri);
        o.w = pk4f8(a[12] * ri, a[13] * ri, a[14] * ri, a[15] * ri);
        *(uint4*)(xa8 + (size_t)node * 256 + 128 + l8 * 16) = o;
    }
}

// gather2: fp8 in/out on h1a8[50000][512] (cols 0..255 = h1 fp8, 256..511 = agg2 fp8)
__global__ __launch_bounds__(256) void gather2_kernel(
    const int* __restrict__ offsets, const int* __restrict__ srcbuf,
    const float* __restrict__ rinv, uchar_t* __restrict__ h1a8)
{
    int node = blockIdx.x * 4 + (threadIdx.x >> 6);
    if (node >= N_NODES) return;
    int lane = threadIdx.x & 63;
    int grp = lane >> 4;
    int l16 = lane & 15;
    int beg = offsets[node], end = offsets[node + 1];

    float a[16];
    #pragma unroll
    for (int k = 0; k < 16; ++k) a[k] = 0.f;

    int j = beg + grp;
    for (; j + 4 < end; j += 8) {
        int s0 = srcbuf[j];
        int s1 = srcbuf[j + 4];
        uint4 u0 = *(const uint4*)(h1a8 + (size_t)s0 * 512 + l16 * 16);
        uint4 u1 = *(const uint4*)(h1a8 + (size_t)s1 * 512 + l16 * 16);
        accf8(u0.x, a + 0); accf8(u0.y, a + 4); accf8(u0.z, a + 8); accf8(u0.w, a + 12);
        accf8(u1.x, a + 0); accf8(u1.y, a + 4); accf8(u1.z, a + 8); accf8(u1.w, a + 12);
    }
    for (; j < end; j += 4) {
        int s0 = srcbuf[j];
        uint4 u0 = *(const uint4*)(h1a8 + (size_t)s0 * 512 + l16 * 16);
        accf8(u0.x, a + 0); accf8(u0.y, a + 4); accf8(u0.z, a + 8); accf8(u0.w, a + 12);
    }
    #pragma unroll
    for (int k = 0; k < 16; ++k) a[k] += __shfl_down(a[k], 32);
    #pragma unroll
    for (int k = 0; k < 16; ++k) a[k] += __shfl_down(a[k], 16);
    if (grp == 0) {
        float ri = rinv[node];
        uint4 o;
        o.x = pk4f8(a[0] * ri,  a[1] * ri,  a[2] * ri,  a[3] * ri);
        o.y = pk4f8(a[4] * ri,  a[5] * ri,  a[6] * ri,  a[7] * ri);
        o.z = pk4f8(a[8] * ri,  a[9] * ri,  a[10] * ri, a[11] * ri);
        o.w = pk4f8(a[12] * ri, a[13] * ri, a[14] * ri, a[15] * ri);
        *(uint4*)(h1a8 + (size_t)node * 512 + 256 + l16 * 16) = o;
    }
}

// ---------------- fp8 MFMA GEMM (128x128 tile, BK=128 fp8, XCD-swizzled) ----------------
// POOL=false: relu(acc+bias) -> fp8 to outf8 (row stride OUTSTR) at col0.
// POOL=true : pool rows by batch[] into psum.
template<int KTOT, int OUTSTR, bool POOL, int COLS>
__global__ __launch_bounds__(256) void mfma_gemm_f8(
    const uchar_t* __restrict__ A, const uchar_t* __restrict__ Bt,
    const float* __restrict__ bias, uchar_t* __restrict__ outf8,
    float* __restrict__ psum, const int* __restrict__ batch)
{
    __shared__ uchar_t As[16384];       // 128 rows x 128 B (BK=128)
    __shared__ uchar_t Bs[16384];
    __shared__ float pool2[8 * 128];

    const int id = blockIdx.x;
    const int xcd = id & 7;
    const int s_ = id >> 3;
    const int col = s_ & (COLS - 1);
    const int rloc = s_ / COLS;
    const int rowblk = xcd * RPX + rloc;
    if (rowblk >= RB) return;

    const int tid = threadIdx.x;
    const int lane = tid & 63;
    const int wave = tid >> 6;
    const int quad = lane >> 4;
    const int l16 = lane & 15;
    const int m0w = (wave & 1) * 64;
    const int n0w = (wave >> 1) * 64;
    const int row0 = rowblk * 128;
    const int col0 = col * 128;
    const int Mm1 = N_NODES - 1;

    int st_r[4], st_q[4];
    #pragma unroll
    for (int c = 0; c < 4; ++c) {
        int slot = c * 256 + tid;
        int r = slot >> 3;
        st_r[c] = r;
        st_q[c] = ((slot & 7) ^ (r & 7)) * 16;   // byte offset
    }

    floatx4 acc[4][4] = {};

    for (int kt = 0; kt < KTOT / 128; ++kt) {
        const int kb = kt * 128;
        #pragma unroll
        for (int c = 0; c < 4; ++c) {
            async16(A + (size_t)min(row0 + st_r[c], Mm1) * KTOT + kb + st_q[c],
                    &As[(c * 256 + wave * 64) * 16]);
        }
        #pragma unroll
        for (int c = 0; c < 4; ++c) {
            async16(Bt + (size_t)(col0 + st_r[c]) * KTOT + kb + st_q[c],
                    &Bs[(c * 256 + wave * 64) * 16]);
        }
        __syncthreads();
        #pragma unroll
        for (int kk = 0; kk < 4; ++kk) {
            const int c0 = kk * 2 + (quad >> 1);
            const int o8 = (quad & 1) * 8;
            long a[4], b[4];
            #pragma unroll
            for (int t = 0; t < 4; ++t) {
                int r = m0w + t * 16 + l16;
                a[t] = *(const long*)&As[r * 128 + ((c0 ^ (r & 7)) * 16) + o8];
            }
            #pragma unroll
            for (int t = 0; t < 4; ++t) {
                int r = n0w + t * 16 + l16;
                b[t] = *(const long*)&Bs[r * 128 + ((c0 ^ (r & 7)) * 16) + o8];
            }
            #pragma unroll
            for (int i = 0; i < 4; ++i)
                #pragma unroll
                for (int j = 0; j < 4; ++j)
                    acc[i][j] = __builtin_amdgcn_mfma_f32_16x16x32_fp8_fp8(a[i], b[j], acc[i][j], 0, 0, 0);
        }
        __syncthreads();
    }

    float bias4[4];
    #pragma unroll
    for (int j = 0; j < 4; ++j) bias4[j] = bias[col0 + n0w + j * 16 + l16];

    if (!POOL) {
        #pragma unroll
        for (int i = 0; i < 4; ++i) {
            #pragma unroll
            for (int r = 0; r < 4; ++r) {
                int m = row0 + m0w + i * 16 + quad * 4 + r;
                if (m < N_NODES) {
                    #pragma unroll
                    for (int j = 0; j < 4; ++j) {
                        float v = fmaxf(acc[i][j][r] + bias4[j], 0.f);
                        outf8[(size_t)m * OUTSTR + col0 + n0w + j * 16 + l16] = f2f8(v);
                    }
                }
            }
        }
    } else {
        int gmin = batch[row0];
        int gmax = batch[min(row0 + 127, N_NODES - 1)];
        int span = gmax - gmin + 1;
        if (span == 1) {
            float s[4] = {0.f, 0.f, 0.f, 0.f};
            #pragma unroll
            for (int i = 0; i < 4; ++i) {
                #pragma unroll
                for (int r = 0; r < 4; ++r) {
                    int m = row0 + m0w + i * 16 + quad * 4 + r;
                    if (m < N_NODES) {
                        #pragma unroll
                        for (int j = 0; j < 4; ++j)
                            s[j] += fmaxf(acc[i][j][r] + bias4[j], 0.f);
                    }
                }
            }
            int slot = (wave & 1) * 4 + quad;
            #pragma unroll
            for (int j = 0; j < 4; ++j)
                pool2[slot * 128 + n0w + j * 16 + l16] = s[j];
            __syncthreads();
            if (tid < 128) {
                float v = 0.f;
                #pragma unroll
                for (int k = 0; k < 8; ++k) v += pool2[k * 128 + tid];
                atomicAdd(psum + (size_t)gmin * HID + col0 + tid, v);
            }
        } else if (span <= 8) {
            for (int i = tid; i < span * 128; i += 256) pool2[i] = 0.f;
            __syncthreads();
            float s[4] = {0.f, 0.f, 0.f, 0.f};
            int cg = -1;
            #pragma unroll
            for (int i = 0; i < 4; ++i) {
                #pragma unroll
                for (int r = 0; r < 4; ++r) {
                    int m = row0 + m0w + i * 16 + quad * 4 + r;
                    if (m < N_NODES) {
                        int g = batch[m] - gmin;
                        if (g != cg) {
                            if (cg >= 0) {
                                #pragma unroll
                                for (int j = 0; j < 4; ++j)
                                    atomicAdd(&pool2[cg * 128 + n0w + j * 16 + l16], s[j]);
                            }
                            cg = g;
                            s[0] = s[1] = s[2] = s[3] = 0.f;
                        }
                        #pragma unroll
                        for (int j = 0; j < 4; ++j)
                            s[j] += fmaxf(acc[i][j][r] + bias4[j], 0.f);
                    }
                }
            }
            if (cg >= 0) {
                #pragma unroll
                for (int j = 0; j < 4; ++j)
                    atomicAdd(&pool2[cg * 128 + n0w + j * 16 + l16], s[j]);
            }
            __syncthreads();
            for (int i = tid; i < span * 128; i += 256) {
                float v = pool2[i];
                if (v != 0.f)
                    atomicAdd(psum + (size_t)(gmin + (i >> 7)) * HID + col0 + (i & 127), v);
            }
        } else {
            #pragma unroll
            for (int i = 0; i < 4; ++i) {
                #pragma unroll
                for (int r = 0; r < 4; ++r) {
                    int m = row0 + m0w + i * 16 + quad * 4 + r;
                    if (m < N_NODES) {
                        int g = batch[m];
                        #pragma unroll
                        for (int j = 0; j < 4; ++j) {
                            float v = fmaxf(acc[i][j][r] + bias4[j], 0.f);
                            atomicAdd(psum + (size_t)g * HID + col0 + n0w + j * 16 + l16, v);
                        }
                    }
                }
            }
        }
    }
}

// ---------------- head ----------------
__global__ __launch_bounds__(64) void head_hc_kernel(
    const float* __restrict__ psum, const float* __restrict__ ncnt,
    const float* __restrict__ Wh, const float* __restrict__ bh,
    const float* __restrict__ Wc, const float* __restrict__ bc,
    float* __restrict__ out)
{
    __shared__ float p[HID];
    const int tile = blockIdx.x, g = blockIdx.y, t = threadIdx.x;
    float inv = 1.0f / fmaxf(ncnt[g], 1.0f);
    #pragma unroll
    for (int i = 0; i < 8; ++i)
        p[i * 64 + t] = psum[(size_t)g * HID + i * 64 + t] * inv;
    __syncthreads();
    int col = tile * 64 + t;
    float h = bh[col], c = bc[col];
    #pragma unroll 8
    for (int k = 0; k < HID; ++k) {
        float pk = p[k];
        h += pk * Wh[(size_t)k * HID + col];
        c += pk * Wc[(size_t)k * HID + col];
    }
    out[(size_t)N_GRAPHS * VOCAB + (size_t)g * HID + col] = h;       // hidden
    out[(size_t)2 * N_GRAPHS * VOCAB + (size_t)g * HID + col] = c;   // cell
}

__global__ __launch_bounds__(512) void head_out_kernel(
    const float* __restrict__ hidden, const float* __restrict__ Wout,
    const float* __restrict__ bout, float* __restrict__ out)
{
    __shared__ float hrow[HID];
    __shared__ float redm[8];
    __shared__ float reds[8];
    __shared__ float bm, bs;
    const int g = blockIdx.x, j = threadIdx.x;
    hrow[j] = hidden[(size_t)g * HID + j];
    __syncthreads();
    float l = bout[j];
    #pragma unroll 8
    for (int k = 0; k < HID; ++k)
        l += hrow[k] * Wout[(size_t)k * VOCAB + j];

    const int lane = j & 63, wave = j >> 6;
    float m = l;
    #pragma unroll
    for (int o = 32; o > 0; o >>= 1) m = fmaxf(m, __shfl_down(m, o));
    if (lane == 0) redm[wave] = m;
    __syncthreads();
    if (j == 0) {
        float mm = redm[0];
        for (int w = 1; w < 8; ++w) mm = fmaxf(mm, redm[w]);
        bm = mm;
    }
    __syncthreads();
    m = bm;
    float e = __expf(l - m);
    float s = e;
    #pragma unroll
    for (int o = 32; o > 0; o >>= 1) s += __shfl_down(s, o);
    if (lane == 0) reds[wave] = s;
    __syncthreads();
    if (j == 0) {
        float ss = 0.f;
        for (int w = 0; w < 8; ++w) ss += reds[w];
        bs = ss;
    }
    __syncthreads();
    out[(size_t)g * VOCAB + j] = l - m - logf(bs);                  // logits
}

// ---------------- launch ----------------
extern "C" void kernel_launch(void* const* d_in, const int* in_sizes, int n_in,
                              void* d_out, int out_size, void* d_ws, size_t ws_size,
                              hipStream_t stream) {
    const float* x      = (const float*)d_in[1];
    const int*   edge   = (const int*)d_in[2];
    const int*   batch  = (const int*)d_in[3];
    const float* Wroot1 = (const float*)d_in[4];
    const float* Wrel1  = (const float*)d_in[5];
    const float* b1     = (const float*)d_in[6];
    const float* Wroot2 = (const float*)d_in[7];
    const float* Wrel2  = (const float*)d_in[8];
    const float* b2     = (const float*)d_in[9];
    const float* Wh     = (const float*)d_in[10];
    const float* bh     = (const float*)d_in[11];
    const float* Wc     = (const float*)d_in[12];
    const float* bc     = (const float*)d_in[13];
    const float* Wout   = (const float*)d_in[14];
    const float* bout   = (const float*)d_in[15];
    float* out = (float*)d_out;

    // workspace layout: deg+psum first (single minimal memset)
    int*      deg_i   = (int*)d_ws;                        // 50000 (zeroed)
    float*    psum    = (float*)(deg_i + N_NODES);         // 32768 (zeroed)
    int*      cursor  = (int*)(psum + N_GRAPHS * HID);     // 50000 (init by scan_final)
    float*    ncnt    = (float*)(cursor + N_NODES);        // 64
    int*      offsets = (int*)(ncnt + N_GRAPHS);           // 50001
    int*      srcbuf  = offsets + (N_NODES + 1);           // 800000
    int*      bsum    = srcbuf + N_EDGES;                  // 256
    int*      pad_    = bsum + 256;                        // 256
    float*    rinv    = (float*)(pad_ + 256);              // 50000 (+3 pad for 16B align)
    uchar_t*  xa8     = (uchar_t*)(rinv + N_NODES + 3);    // 50000*256 fp8
    uchar_t*  w1t8    = xa8 + (size_t)N_NODES * 256;       // 256*256 fp8
    uchar_t*  h1a8    = w1t8 + 256 * 256;                  // 50000*512 fp8
    uchar_t*  w2t8    = h1a8 + (size_t)N_NODES * 512;      // 512*512 fp8

    hipMemsetAsync(d_ws, 0, (size_t)(N_NODES + N_GRAPHS * HID) * 4, stream);

    prep_kernel<<<DEG_BLOCKS + CONV_BLOCKS, 256, 0, stream>>>(
        edge, deg_i, x, Wroot1, Wrel1, Wroot2, Wrel2, xa8, w1t8, w2t8);
    scan_part_kernel<<<SCAN_NB, SCAN_B, 0, stream>>>(deg_i, bsum);
    scan_final_kernel<<<SCAN_NB, SCAN_B, 0, stream>>>(
        deg_i, bsum, offsets, cursor, rinv, batch, ncnt);
    fill_kernel<<<8 * NBF, 256, 0, stream>>>(edge, cursor, srcbuf);

    gather1_kernel<<<(N_NODES + 3) / 4, 256, 0, stream>>>(offsets, srcbuf, rinv, xa8);

    {   // layer 1: A=xa8 [50000 x 256] fp8, B=w1t8 fp8 -> h1a8 cols 0..255 fp8; COLS=2
        mfma_gemm_f8<256, 512, false, 2><<<8 * RPX * 2, 256, 0, stream>>>(
            xa8, w1t8, b1, h1a8, nullptr, nullptr);
    }

    gather2_kernel<<<(N_NODES + 3) / 4, 256, 0, stream>>>(offsets, srcbuf, rinv, h1a8);

    {   // layer 2: A=h1a8 [50000 x 512] fp8, B=w2t8 fp8 -> pooled psum; COLS=4
        mfma_gemm_f8<512, 0, true, 4><<<8 * RPX * 4, 256, 0, stream>>>(
            h1a8, w2t8, b2, nullptr, psum, batch);
    }

    head_hc_kernel<<<dim3(8, 64), 64, 0, stream>>>(psum, ncnt, Wh, bh, Wc, bc, out);
    head_out_kernel<<<N_GRAPHS, 512, 0, stream>>>(
        out + (size_t)N_GRAPHS * VOCAB, Wout, bout, out);
}